// Round 10
// baseline (162.482 us; speedup 1.0000x reference)
//
#include <hip/hip_runtime.h>
#include <hip/hip_cooperative_groups.h>
#include <cstdint>
#include <cstddef>

namespace cg = cooperative_groups;

typedef unsigned long long ull;
typedef unsigned short u16;

#define N 8192
#define NWORDS 128          // 8192 / 64
#define NPOST 2000
#define NMS_THR 0.7f
#define SPLIT 8
#define SLICE (N / SPLIT)   // 1024
#define MASKW 48            // words covered by sparse conflict pairs (stop ~34)
#define CCAP 128            // cross-word pair cap per word
#define ICAP 16             // in-word pair cap per word
#define NUNITS 312          // pair blocks: sum_{cbq<12} min(48,4cbq+4) = 312

// ---------------- ws layout (same as round 9) ----------------
// 0      : partial  u16[8*8192]   128 KiB
// 131072 : bs       float4[8192]  128 KiB (sorted clipped boxes)
// 262144 : area     f32[8192]     32 KiB
// 294912 : invBits  ull[128]      1 KiB
// 295936 : ctrl     i32[64]       ([0..47] crossCnt, [48] overflow)
// 296192 : inCnt    i32[64]
// 296448 : crossBuf u32[48*128]   24 KiB
// 321024 : inBuf    u32[48*16]    3 KiB

// ---------------------------------------------------------------------------
__device__ __forceinline__ float4 decode_clip_box(const float4 L, bool* valid) {
#pragma clang fp contract(off)
  float cy = L.x, cx = L.y, h = L.z, w = L.w;
  float y1 = cy - 0.5f * h;
  float x1 = cx - 0.5f * w;
  float y2 = cy + 0.5f * h;
  float x2 = cx + 0.5f * w;
  *valid = ((y2 - y1) > 16.0f) && ((x2 - x1) > 16.0f);
  float4 b;
  b.x = fminf(fmaxf(y1, 0.0f), 800.0f);
  b.y = fminf(fmaxf(x1, 0.0f), 800.0f);
  b.z = fminf(fmaxf(y2, 0.0f), 800.0f);
  b.w = fminf(fmaxf(x2, 0.0f), 800.0f);
  return b;
}

__device__ __forceinline__ float box_area(const float4 b) {
#pragma clang fp contract(off)
  return (b.z - b.x) * (b.w - b.y);
}

__device__ __forceinline__ bool iou_gt_thr(const float4 a, float aa,
                                           const float4 b, float ab) {
#pragma clang fp contract(off)
  float iy = fminf(a.z, b.z) - fmaxf(a.x, b.x);
  float ix = fminf(a.w, b.w) - fmaxf(a.y, b.y);
  iy = fmaxf(iy, 0.0f);
  ix = fmaxf(ix, 0.0f);
  float inter = iy * ix;
  float uni = aa + ab - inter;
  // exact IEEE division: predicate must bit-match the numpy reference
  return (inter > 0.0f) && (uni > 0.0f) && ((inter / uni) > NMS_THR);
}

__device__ __forceinline__ ull wave_or64(ull v) {
  #pragma unroll
  for (int m = 1; m < 64; m <<= 1) {
    unsigned lo = __shfl_xor((unsigned)v, m, 64);
    unsigned hi = __shfl_xor((unsigned)(v >> 32), m, 64);
    v |= ((ull)hi << 32) | (ull)lo;
  }
  return v;
}

// Greedy within-word resolve from "who-I-suppress" masks (fallback path).
__device__ __forceinline__ ull resolve_word(ull dg, ull avail, int lane) {
  ull conflict = __ballot(((dg & avail) != 0ull) && ((avail >> lane) & 1ull));
  if (conflict == 0ull) return avail;
  ull dgT = 0ull;
  #pragma unroll
  for (int c = 0; c < 64; ++c) {
    ull tb = __ballot((dg >> c) & 1ull);
    if (lane == c) dgT = tb;
  }
  ull kept = avail;
  while (true) {                 // fixpoint == greedy (prefix-stabilization)
    bool sup = (dgT & kept) != 0ull;
    ull kn = avail & ~__ballot(sup);
    if (kn == kept) break;
    kept = kn;
  }
  return kept;
}

// ===========================================================================
// FUSED COOPERATIVE KERNEL: rank -> gather -> pairs -> scan, one dispatch.
// 256 blocks x 256 threads (1 block/CU), grid.sync() between phases.
// ===========================================================================
__global__ __launch_bounds__(256) void fused_kernel(
    const float* __restrict__ locs, const float* __restrict__ scores,
    u16* __restrict__ partial, float4* __restrict__ bs,
    float* __restrict__ area, ull* __restrict__ invBits,
    int* __restrict__ ctrl, int* __restrict__ inCnt,
    unsigned* __restrict__ crossBuf, unsigned* __restrict__ inBuf,
    float* __restrict__ out) {
  cg::grid_group grid = cg::this_grid();
  __shared__ __align__(16) char smem[36864];
  int tid = threadIdx.x;
  int bid = blockIdx.x;

  // ---------------- Phase 1: init + rank partial counts ----------------
  if (bid == 0) {
    if (tid < NWORDS) invBits[tid] = 0ull;
    else if (tid < NWORDS + 64) ctrl[tid - NWORDS] = 0;
    else if (tid < NWORDS + 128) inCnt[tid - NWORDS - 64] = 0;
  }
  {
    float* ssc = (float*)smem;                   // 4 KiB slice scores
    int bx = bid & 31, s = bid >> 5;
    const float4* locs4 = (const float4*)locs;
    for (int k = tid; k < SLICE; k += 256) {
      int j = s * SLICE + k;
      bool v; (void)decode_clip_box(locs4[j], &v);
      ssc[k] = v ? scores[j] : -__builtin_inff();
    }
    int i = bx * 256 + tid;
    bool vi; (void)decode_clip_box(locs4[i], &vi);
    float si = vi ? scores[i] : -__builtin_inff();
    __syncthreads();
    // j precedes i <=> s_j > s_i || (s_j == s_i && j < i)  (stable descending)
    int j0 = s * SLICE;
    int cnt = 0;
    const float4* s4 = (const float4*)ssc;
    for (int q = 0; q < SLICE / 4; ++q) {
      float4 v = s4[q];                          // LDS broadcast
      int j = j0 + q * 4;
      cnt += (v.x > si) || ((v.x == si) & ((j + 0) < i));
      cnt += (v.y > si) || ((v.y == si) & ((j + 1) < i));
      cnt += (v.z > si) || ((v.z == si) & ((j + 2) < i));
      cnt += (v.w > si) || ((v.w == si) & ((j + 3) < i));
    }
    partial[s * N + i] = (u16)cnt;
  }
  grid.sync();

  // ---------------- Phase 2: gather into sorted order ----------------
  if (bid < 32) {
    int i = bid * 256 + tid;
    int r = 0;
    #pragma unroll
    for (int s = 0; s < SPLIT; ++s) r += (int)partial[s * N + i];
    bool v;
    float4 b = decode_clip_box(((const float4*)locs)[i], &v);
    bs[r] = b;
    area[r] = box_area(b);
    if (!v) atomicOr(&invBits[r >> 6], 1ull << (r & 63));
  }
  grid.sync();

  // ---------------- Phase 3: sparse conflict pairs ----------------
  {
    float4* sb = (float4*)smem;                  // [4][64]
    float*  sa = (float*)(smem + 4096);          // [4][64]
    for (int u = bid; u < NUNITS; u += 256) {
      __syncthreads();                           // smem reuse across iters
      // map u -> (cbq, rb); S(c) = 2c(c+1)
      int cbq = 0;
      while (2 * (cbq + 1) * (cbq + 2) <= u) ++cbq;
      int rb = u - 2 * cbq * (cbq + 1);
      int lane = tid & 63;
      int cq = tid >> 6;
      int cb = cbq * 4 + cq;
      int j0 = cb * 64;
      sb[cq * 64 + lane] = bs[j0 + lane];
      sa[cq * 64 + lane] = area[j0 + lane];
      int i = rb * 64 + lane;
      float4 r = bs[i];
      float ai = area[i];
      bool vi = !((invBits[rb] >> lane) & 1ull);
      ull invC = invBits[cb];
      __syncthreads();
      bool active = (cb >= rb) && vi;
      if (active) {
        ull bits = 0;
        for (int c = 0; c < 64; ++c) {
          if ((j0 + c) > i && iou_gt_thr(r, ai, sb[cq * 64 + c], sa[cq * 64 + c]))
            bits |= 1ull << c;
        }
        bits &= ~invC;                           // invalid j never kept
        int n = (int)__popcll(bits);
        if (n) {
          if (cb == rb) {                        // in-word pairs
            int base = atomicAdd(&inCnt[cb], n);
            if (base + n > ICAP) { ctrl[48] = 1; }
            else {
              int k = base;
              while (bits) {
                int c = (int)__builtin_ctzll(bits); bits &= bits - 1;
                inBuf[cb * ICAP + k++] = ((unsigned)c << 8) | (unsigned)lane;
              }
            }
          } else {                               // cross-word pairs
            int base = atomicAdd(&ctrl[cb], n);
            if (base + n > CCAP) { ctrl[48] = 1; }
            else {
              int k = base;
              while (bits) {
                int c = (int)__builtin_ctzll(bits); bits &= bits - 1;
                crossBuf[cb * CCAP + k++] = ((unsigned)c << 16) | (unsigned)i;
              }
            }
          }
        }
      }
    }
  }
  grid.sync();
  if (bid != 0) return;

  // ---------------- Phase 4: greedy scan (block 0 only) ----------------
  unsigned (*sCross)[CCAP] = (unsigned(*)[CCAP])(smem + 0);      // 24 KiB
  unsigned (*sIn)[ICAP]    = (unsigned(*)[ICAP])(smem + 24576);  // 3 KiB
  int*  sCCnt     = (int*)(smem + 27648);
  int*  sICnt     = (int*)(smem + 27840);
  ull*  sKeptBits = (ull*)(smem + 28032);
  ull*  sRemv     = (ull*)(smem + 29056);
  u16*  sKeptList = (u16*)(smem + 30080);        // 4000 B
  float4* sWB     = (float4*)(smem + 34080);
  float*  sWA     = (float*)(smem + 35104);
  ull*  sSupW     = (ull*)(smem + 35360);
  int*  sCtl      = (int*)(smem + 35368);        // [0]=base [1]=stop [2]=over

  if (tid < MASKW) { sCCnt[tid] = ctrl[tid]; sICnt[tid] = inCnt[tid]; }
  if (tid == 255) sCtl[2] = ctrl[48];
  if (tid == 254) sCtl[0] = 0;
  if (tid == 253) sCtl[1] = 0;
  if (tid < NWORDS) { sRemv[tid] = invBits[tid]; sKeptBits[tid] = 0ull; }
  for (int k = tid; k < MASKW * CCAP; k += 256)
    ((unsigned*)sCross)[k] = crossBuf[k];
  for (int k = tid; k < MASKW * ICAP; k += 256)
    ((unsigned*)sIn)[k] = inBuf[k];
  __syncthreads();

  int sOver = sCtl[2];
  // ---- sparse masked phase (wave 0 only)
  if (!sOver && tid < 64) {
    int lane = tid;
    int base = 0;
    for (int w = 0; w < MASKW; ++w) {
      ull avail = ~sRemv[w];
      int cnC = sCCnt[w];
      if (cnC > 0) {                             // lane-parallel cross pairs
        ull csup = 0;
        for (int k = lane; k < cnC; k += 64) {
          unsigned p = sCross[w][k];
          int ii = (int)(p & 0xFFFFu);
          int jl = (int)(p >> 16) & 63;
          if ((sKeptBits[ii >> 6] >> (ii & 63)) & 1ull) csup |= 1ull << jl;
        }
        csup = wave_or64(csup);
        avail &= ~csup;
      }
      int cnI = sICnt[w];
      ull kept;
      if (cnI == 0) {
        kept = avail;
      } else {
        ull dgT = 0ull;                          // my in-word suppressors
        for (int k = 0; k < cnI; ++k) {
          unsigned p = sIn[w][k];                // uniform LDS read
          int il = (int)(p & 63u);
          int jl = (int)(p >> 8) & 63;
          if (lane == jl) dgT |= 1ull << il;
        }
        ull cf = __ballot(((dgT & avail) != 0ull) && ((avail >> lane) & 1ull));
        if (cf == 0ull) {
          kept = avail;
        } else {
          kept = avail;
          while (true) {                         // fixpoint == greedy
            bool sup = (dgT & kept) != 0ull;
            ull kn = avail & ~__ballot(sup);
            if (kn == kept) break;
            kept = kn;
          }
        }
      }
      if (lane == 0) sKeptBits[w] = kept;        // same-wave order: ok
      if ((kept >> lane) & 1ull) {
        int rank = base + (int)__popcll(kept & ((1ull << lane) - 1ull));
        if (rank < NPOST) sKeptList[rank] = (u16)(w * 64 + lane);
      }
      base += (int)__popcll(kept);
      if (base >= NPOST) break;                  // ranks >=2000 never emitted
    }
    if (lane == 0) { sCtl[0] = base; if (base >= NPOST) sCtl[1] = 1; }
  }
  __syncthreads();

  // ---- dense fallback (correctness only; not hit by the bench input)
  int startW = sOver ? 0 : MASKW;
  if (!sCtl[1]) {
    for (int w = startW; w < NWORDS; ++w) {
      if (tid < 64) { sWB[tid] = bs[w * 64 + tid]; sWA[tid] = area[w * 64 + tid]; }
      if (tid == 0) *sSupW = sRemv[w];
      __syncthreads();
      int nk = sCtl[0];
      int c = tid & 63;
      for (int k0 = tid >> 6; k0 < nk; k0 += 4) {   // wave per kept box
        int ki = sKeptList[k0];
        float4 kb = bs[ki];                         // uniform load
        bool s = iou_gt_thr(kb, area[ki], sWB[c], sWA[c]);
        ull bits = __ballot(s);
        if (c == 0 && bits) atomicOr(sSupW, bits);
      }
      __syncthreads();
      if (tid < 64) {
        int lane = tid;
        float4 bm = sWB[lane];
        float am = sWA[lane];
        ull dg = 0;
        for (int cc = lane + 1; cc < 64; ++cc)
          if (iou_gt_thr(bm, am, sWB[cc], sWA[cc])) dg |= 1ull << cc;
        ull avail = ~*sSupW;
        ull kept = resolve_word(dg, avail, lane);
        int base = sCtl[0];
        if ((kept >> lane) & 1ull) {
          int rank = base + (int)__popcll(kept & ((1ull << lane) - 1ull));
          if (rank < NPOST) sKeptList[rank] = (u16)(w * 64 + lane);
        }
        if (lane == 0) {
          int nb = base + (int)__popcll(kept);
          sCtl[0] = nb;
          if (nb >= NPOST) sCtl[1] = 1;
        }
      }
      __syncthreads();
      if (sCtl[1]) break;
    }
  }

  __syncthreads();
  int total = sCtl[0];
  if (total > NPOST) total = NPOST;
  for (int r = tid; r < NPOST; r += 256) {
    float4 v = make_float4(0.0f, 0.0f, 0.0f, 0.0f);
    if (r < total) v = bs[sKeptList[r]];
    reinterpret_cast<float4*>(out)[r] = v;
  }
}

// ===========================================================================
// FALLBACK: round-9's proven 4-kernel pipeline (used only if cooperative
// launch is rejected, e.g. not graph-capturable).
// ===========================================================================
__global__ __launch_bounds__(256) void rankpart_kernel(
    const float* __restrict__ locs, const float* __restrict__ scores,
    u16* __restrict__ partial, ull* __restrict__ invBits,
    int* __restrict__ ctrl, int* __restrict__ inCnt) {
  __shared__ float ssc[SLICE];
  int bx = blockIdx.x, s = blockIdx.y;
  int tid = threadIdx.x;
  if (bx == 0 && s == 0) {
    if (tid < NWORDS) invBits[tid] = 0ull;
    else if (tid < NWORDS + 64) ctrl[tid - NWORDS] = 0;
    else if (tid < NWORDS + 112) inCnt[tid - NWORDS - 64] = 0;
  }
  const float4* locs4 = (const float4*)locs;
  for (int k = tid; k < SLICE; k += 256) {
    int j = s * SLICE + k;
    bool v; (void)decode_clip_box(locs4[j], &v);
    ssc[k] = v ? scores[j] : -__builtin_inff();
  }
  int i = bx * 256 + tid;
  bool vi; (void)decode_clip_box(locs4[i], &vi);
  float si = vi ? scores[i] : -__builtin_inff();
  __syncthreads();
  int j0 = s * SLICE;
  int cnt = 0;
  const float4* s4 = (const float4*)ssc;
  for (int q = 0; q < SLICE / 4; ++q) {
    float4 v = s4[q];
    int j = j0 + q * 4;
    cnt += (v.x > si) || ((v.x == si) & ((j + 0) < i));
    cnt += (v.y > si) || ((v.y == si) & ((j + 1) < i));
    cnt += (v.z > si) || ((v.z == si) & ((j + 2) < i));
    cnt += (v.w > si) || ((v.w == si) & ((j + 3) < i));
  }
  partial[s * N + i] = (u16)cnt;
}

__global__ __launch_bounds__(256) void gather_kernel(
    const float* __restrict__ locs, const u16* __restrict__ partial,
    float4* __restrict__ bs, float* __restrict__ area,
    ull* __restrict__ invBits) {
  int i = blockIdx.x * 256 + threadIdx.x;
  int r = 0;
  #pragma unroll
  for (int s = 0; s < SPLIT; ++s) r += (int)partial[s * N + i];
  bool v;
  float4 b = decode_clip_box(((const float4*)locs)[i], &v);
  bs[r] = b;
  area[r] = box_area(b);
  if (!v) atomicOr(&invBits[r >> 6], 1ull << (r & 63));
}

__global__ __launch_bounds__(256) void pairs_kernel(
    const float4* __restrict__ bs, const float* __restrict__ area,
    const ull* __restrict__ invBits,
    int* __restrict__ ctrl, int* __restrict__ inCnt,
    unsigned* __restrict__ crossBuf, unsigned* __restrict__ inBuf) {
  int cbq = blockIdx.x;
  int rb  = blockIdx.y;
  if (cbq * 4 + 3 < rb) return;
  int t = threadIdx.x;
  int lane = t & 63;
  int cq = t >> 6;
  int cb = cbq * 4 + cq;
  __shared__ float4 sb[4][64];
  __shared__ float  sa[4][64];
  int j0 = cb * 64;
  sb[cq][lane] = bs[j0 + lane];
  sa[cq][lane] = area[j0 + lane];
  int i = rb * 64 + lane;
  float4 r = bs[i];
  float ai = area[i];
  bool vi = !((invBits[rb] >> lane) & 1ull);
  ull invC = invBits[cb];
  __syncthreads();
  if (cb < rb || !vi) return;
  ull bits = 0;
  for (int c = 0; c < 64; ++c) {
    if ((j0 + c) > i && iou_gt_thr(r, ai, sb[cq][c], sa[cq][c])) bits |= 1ull << c;
  }
  bits &= ~invC;
  int n = (int)__popcll(bits);
  if (!n) return;
  if (cb == rb) {
    int base = atomicAdd(&inCnt[cb], n);
    if (base + n > ICAP) { ctrl[48] = 1; return; }
    int k = base;
    while (bits) {
      int c = (int)__builtin_ctzll(bits); bits &= bits - 1;
      inBuf[cb * ICAP + k++] = ((unsigned)c << 8) | (unsigned)lane;
    }
  } else {
    int base = atomicAdd(&ctrl[cb], n);
    if (base + n > CCAP) { ctrl[48] = 1; return; }
    int k = base;
    while (bits) {
      int c = (int)__builtin_ctzll(bits); bits &= bits - 1;
      crossBuf[cb * CCAP + k++] = ((unsigned)c << 16) | (unsigned)i;
    }
  }
}

__global__ __launch_bounds__(256) void scan_kernel(
    const ull* __restrict__ invBits, const int* __restrict__ ctrl,
    const int* __restrict__ inCnt, const unsigned* __restrict__ crossBuf,
    const unsigned* __restrict__ inBuf,
    const float4* __restrict__ bs, const float* __restrict__ area,
    float* __restrict__ out) {
  __shared__ unsigned sCross[MASKW][CCAP];
  __shared__ unsigned sIn[MASKW][ICAP];
  __shared__ int sCCnt[MASKW];
  __shared__ int sICnt[MASKW];
  __shared__ ull sKeptBits[NWORDS];
  __shared__ ull sRemv[NWORDS];
  __shared__ u16 sKeptList[NPOST];
  __shared__ float4 sWB[64];
  __shared__ float  sWA[64];
  __shared__ ull sSupW;
  __shared__ int sKeptBase, sStop, sOver;
  int tid = threadIdx.x;

  if (tid < MASKW) { sCCnt[tid] = ctrl[tid]; sICnt[tid] = inCnt[tid]; }
  if (tid == 255) sOver = ctrl[48];
  if (tid == 254) sKeptBase = 0;
  if (tid == 253) sStop = 0;
  if (tid < NWORDS) { sRemv[tid] = invBits[tid]; sKeptBits[tid] = 0ull; }
  for (int k = tid; k < MASKW * CCAP; k += 256)
    ((unsigned*)sCross)[k] = crossBuf[k];
  for (int k = tid; k < MASKW * ICAP; k += 256)
    ((unsigned*)sIn)[k] = inBuf[k];
  __syncthreads();

  if (!sOver && tid < 64) {
    int lane = tid;
    int base = 0;
    for (int w = 0; w < MASKW; ++w) {
      ull avail = ~sRemv[w];
      int cnC = sCCnt[w];
      if (cnC > 0) {
        ull csup = 0;
        for (int k = lane; k < cnC; k += 64) {
          unsigned p = sCross[w][k];
          int ii = (int)(p & 0xFFFFu);
          int jl = (int)(p >> 16) & 63;
          if ((sKeptBits[ii >> 6] >> (ii & 63)) & 1ull) csup |= 1ull << jl;
        }
        csup = wave_or64(csup);
        avail &= ~csup;
      }
      int cnI = sICnt[w];
      ull kept;
      if (cnI == 0) {
        kept = avail;
      } else {
        ull dgT = 0ull;
        for (int k = 0; k < cnI; ++k) {
          unsigned p = sIn[w][k];
          int il = (int)(p & 63u);
          int jl = (int)(p >> 8) & 63;
          if (lane == jl) dgT |= 1ull << il;
        }
        ull cf = __ballot(((dgT & avail) != 0ull) && ((avail >> lane) & 1ull));
        if (cf == 0ull) {
          kept = avail;
        } else {
          kept = avail;
          while (true) {
            bool sup = (dgT & kept) != 0ull;
            ull kn = avail & ~__ballot(sup);
            if (kn == kept) break;
            kept = kn;
          }
        }
      }
      if (lane == 0) sKeptBits[w] = kept;
      if ((kept >> lane) & 1ull) {
        int rank = base + (int)__popcll(kept & ((1ull << lane) - 1ull));
        if (rank < NPOST) sKeptList[rank] = (u16)(w * 64 + lane);
      }
      base += (int)__popcll(kept);
      if (base >= NPOST) break;
    }
    if (lane == 0) { sKeptBase = base; if (base >= NPOST) sStop = 1; }
  }
  __syncthreads();

  int startW = sOver ? 0 : MASKW;
  if (!sStop) {
    for (int w = startW; w < NWORDS; ++w) {
      if (tid < 64) { sWB[tid] = bs[w * 64 + tid]; sWA[tid] = area[w * 64 + tid]; }
      if (tid == 0) sSupW = sRemv[w];
      __syncthreads();
      int nk = sKeptBase;
      int c = tid & 63;
      for (int k0 = tid >> 6; k0 < nk; k0 += 4) {
        int ki = sKeptList[k0];
        float4 kb = bs[ki];
        bool s = iou_gt_thr(kb, area[ki], sWB[c], sWA[c]);
        ull bits = __ballot(s);
        if (c == 0 && bits) atomicOr(&sSupW, bits);
      }
      __syncthreads();
      if (tid < 64) {
        int lane = tid;
        float4 bm = sWB[lane];
        float am = sWA[lane];
        ull dg = 0;
        for (int cc = lane + 1; cc < 64; ++cc)
          if (iou_gt_thr(bm, am, sWB[cc], sWA[cc])) dg |= 1ull << cc;
        ull avail = ~sSupW;
        ull kept = resolve_word(dg, avail, lane);
        int base = sKeptBase;
        if ((kept >> lane) & 1ull) {
          int rank = base + (int)__popcll(kept & ((1ull << lane) - 1ull));
          if (rank < NPOST) sKeptList[rank] = (u16)(w * 64 + lane);
        }
        if (lane == 0) {
          int nb = base + (int)__popcll(kept);
          sKeptBase = nb;
          if (nb >= NPOST) sStop = 1;
        }
      }
      __syncthreads();
      if (sStop) break;
    }
  }

  __syncthreads();
  int total = sKeptBase;
  if (total > NPOST) total = NPOST;
  for (int r = tid; r < NPOST; r += 256) {
    float4 v = make_float4(0.0f, 0.0f, 0.0f, 0.0f);
    if (r < total) v = bs[sKeptList[r]];
    reinterpret_cast<float4*>(out)[r] = v;
  }
}

// ---------------------------------------------------------------------------
extern "C" void kernel_launch(void* const* d_in, const int* in_sizes, int n_in,
                              void* d_out, int out_size, void* d_ws, size_t ws_size,
                              hipStream_t stream) {
  const float* locs   = (const float*)d_in[0];   // (8192,4) cy,cx,h,w
  const float* scores = (const float*)d_in[1];   // (8192,)

  char* ws = (char*)d_ws;
  u16*      partial  = (u16*)(ws + 0);
  float4*   bs       = (float4*)(ws + 131072);
  float*    area     = (float*)(ws + 262144);
  ull*      invBits  = (ull*)(ws + 294912);
  int*      ctrl     = (int*)(ws + 295936);
  int*      inCnt    = (int*)(ws + 296192);
  unsigned* crossBuf = (unsigned*)(ws + 296448);
  unsigned* inBuf    = (unsigned*)(ws + 321024);
  float*    outp     = (float*)d_out;

  void* args[] = {&locs, &scores, &partial, &bs, &area, &invBits,
                  &ctrl, &inCnt, &crossBuf, &inBuf, &outp};
  hipError_t err = hipLaunchCooperativeKernel(
      (const void*)fused_kernel, dim3(256), dim3(256), args, 0, stream);
  if (err != hipSuccess) {
    (void)hipGetLastError();                     // clear sticky error
    rankpart_kernel<<<dim3(N / 256, SPLIT), 256, 0, stream>>>(
        locs, scores, partial, invBits, ctrl, inCnt);
    gather_kernel<<<N / 256, 256, 0, stream>>>(locs, partial, bs, area, invBits);
    pairs_kernel<<<dim3(MASKW / 4, MASKW), 256, 0, stream>>>(
        bs, area, invBits, ctrl, inCnt, crossBuf, inBuf);
    scan_kernel<<<1, 256, 0, stream>>>(
        invBits, ctrl, inCnt, crossBuf, inBuf, bs, area, outp);
  }
}

// Round 12
// 94.875 us; speedup vs baseline: 1.7126x; 1.7126x over previous
//
#include <hip/hip_runtime.h>
#include <cstdint>
#include <cstddef>

typedef unsigned long long ull;
typedef unsigned short u16;

#define N 8192
#define NWORDS 128          // 8192 / 64
#define NPOST 2000
#define NMS_THR 0.7f
#define MASKW 48            // words covered by sparse conflict pairs (stop ~34)
#define CCAP 128            // cross-word pair cap per word
#define ICAP 16             // in-word pair cap per word
#define NUNITS 312          // pair units: sum_{cbq<12} (4cbq+4) = 312

// ---------------- ws layout ----------------
// 0      : bs       float4[8192]  128 KiB (sorted clipped boxes)
// 131072 : area     f32[8192]     32 KiB  (-1.0 marks invalid box)
// 163840 : ctrl     i32[64]       ([0..47] crossCnt, [48] overflow, [49] done)
// 164096 : inCnt    i32[64]
// 164352 : crossBuf u32[48*128]   24 KiB
// 188928 : inBuf    u32[48*16]    3 KiB

// ---------------------------------------------------------------------------
__device__ __forceinline__ float4 decode_clip_box(const float4 L, bool* valid) {
#pragma clang fp contract(off)
  float cy = L.x, cx = L.y, h = L.z, w = L.w;
  float y1 = cy - 0.5f * h;
  float x1 = cx - 0.5f * w;
  float y2 = cy + 0.5f * h;
  float x2 = cx + 0.5f * w;
  *valid = ((y2 - y1) > 16.0f) && ((x2 - x1) > 16.0f);
  float4 b;
  b.x = fminf(fmaxf(y1, 0.0f), 800.0f);
  b.y = fminf(fmaxf(x1, 0.0f), 800.0f);
  b.z = fminf(fmaxf(y2, 0.0f), 800.0f);
  b.w = fminf(fmaxf(x2, 0.0f), 800.0f);
  return b;
}

__device__ __forceinline__ float box_area(const float4 b) {
#pragma clang fp contract(off)
  return (b.z - b.x) * (b.w - b.y);   // clipped => always >= 0
}

__device__ __forceinline__ bool iou_gt_thr(const float4 a, float aa,
                                           const float4 b, float ab) {
#pragma clang fp contract(off)
  float iy = fminf(a.z, b.z) - fmaxf(a.x, b.x);
  float ix = fminf(a.w, b.w) - fmaxf(a.y, b.y);
  iy = fmaxf(iy, 0.0f);
  ix = fmaxf(ix, 0.0f);
  float inter = iy * ix;
  float uni = aa + ab - inter;
  // exact IEEE division: predicate must bit-match the numpy reference
  return (inter > 0.0f) && (uni > 0.0f) && ((inter / uni) > NMS_THR);
}

__device__ __forceinline__ ull wave_or64(ull v) {
  #pragma unroll
  for (int m = 1; m < 64; m <<= 1) {
    unsigned lo = __shfl_xor((unsigned)v, m, 64);
    unsigned hi = __shfl_xor((unsigned)(v >> 32), m, 64);
    v |= ((ull)hi << 32) | (ull)lo;
  }
  return v;
}

// Greedy within-word resolve (fallback path).
__device__ __forceinline__ ull resolve_word(ull dg, ull avail, int lane) {
  ull conflict = __ballot(((dg & avail) != 0ull) && ((avail >> lane) & 1ull));
  if (conflict == 0ull) return avail;
  ull dgT = 0ull;
  #pragma unroll
  for (int c = 0; c < 64; ++c) {
    ull tb = __ballot((dg >> c) & 1ull);
    if (lane == c) dgT = tb;
  }
  ull kept = avail;
  while (true) {                 // fixpoint == greedy (prefix-stabilization)
    bool sup = (dgT & kept) != 0ull;
    ull kn = avail & ~__ballot(sup);
    if (kn == kept) break;
    kept = kn;
  }
  return kept;
}

__device__ __forceinline__ unsigned aload(const unsigned* p) {
  return __hip_atomic_load(p, __ATOMIC_RELAXED, __HIP_MEMORY_SCOPE_AGENT);
}
__device__ __forceinline__ int aloadi(const int* p) {
  return __hip_atomic_load(p, __ATOMIC_RELAXED, __HIP_MEMORY_SCOPE_AGENT);
}

// ===========================================================================
// K1: rank + gather, fused, no internal cross-block dependency.
// GRID = N/32 = 256 blocks (r11 bug: was 32 -> 7/8 of bs/area stayed poison).
// Block b owns boxes b*32..b*32+31; all 8192 decoded scores staged in LDS;
// thread t computes partial rank of box (t&31) over slice (t>>5).
// area = -1 marks invalid.  Block 0 zeroes K2's counters (kernel-boundary
// visibility -> poison-proof every call).
// ===========================================================================
__global__ __launch_bounds__(256) void rankgather_kernel(
    const float* __restrict__ locs, const float* __restrict__ scores,
    float4* __restrict__ bs, float* __restrict__ area,
    int* __restrict__ ctrl, int* __restrict__ inCnt) {
  __shared__ float ssc[N];            // 32 KiB decoded scores (-inf invalid)
  __shared__ int sRank[32][9];        // +1 pad: conflict-free
  int tid = threadIdx.x, bid = blockIdx.x;
  if (bid == 0) {
    if (tid < 64) ctrl[tid] = 0;
    else if (tid < 128) inCnt[tid - 64] = 0;
  }
  const float4* locs4 = (const float4*)locs;
  for (int k = 0; k < 32; ++k) {
    int j = k * 256 + tid;            // coalesced
    bool v; (void)decode_clip_box(locs4[j], &v);
    ssc[j] = v ? scores[j] : -__builtin_inff();
  }
  __syncthreads();
  int boxOff = tid & 31;
  int part = tid >> 5;                // 8 slices of 1024
  int i = bid * 32 + boxOff;
  float si = ssc[i];
  const float4* s4 = (const float4*)(ssc + part * 1024);
  int j0 = part * 1024;
  int cnt = 0;
  // j precedes i <=> s_j > s_i || (s_j == s_i && j < i)  (stable descending)
  for (int q = 0; q < 256; ++q) {
    float4 v = s4[q];                 // 2 uniform addrs/wave: 2-way (free)
    int j = j0 + 4 * q;
    cnt += (v.x > si) || ((v.x == si) & ((j + 0) < i));
    cnt += (v.y > si) || ((v.y == si) & ((j + 1) < i));
    cnt += (v.z > si) || ((v.z == si) & ((j + 2) < i));
    cnt += (v.w > si) || ((v.w == si) & ((j + 3) < i));
  }
  sRank[boxOff][part] = cnt;
  __syncthreads();
  if (tid < 32) {
    int r = 0;
    #pragma unroll
    for (int p = 0; p < 8; ++p) r += sRank[tid][p];
    int ig = bid * 32 + tid;
    bool v;
    float4 b = decode_clip_box(locs4[ig], &v);
    bs[r] = b;
    area[r] = v ? box_area(b) : -1.0f;   // sign encodes validity
  }
}

// ===========================================================================
// K2: pairs (blocks 1..312) + scan (block 0), single dispatch.
// Handoff: pairs write entries (agent-scope relaxed atomic stores);
// __syncthreads drains; thread 0 fetch_add(ctrl[49], RELEASE).  Block 0
// spins with ACQUIRE agent loads, then reads all pair payload with agent
// relaxed atomic loads (bypass local L1/L2 -> always fresh).
// No deadlock possible: only the consumer waits; producers retire freely.
// ===========================================================================
__global__ __launch_bounds__(256) void pairscan_kernel(
    const float4* __restrict__ bs, const float* __restrict__ area,
    int* __restrict__ ctrl, int* __restrict__ inCnt,
    unsigned* __restrict__ crossBuf, unsigned* __restrict__ inBuf,
    float* __restrict__ out) {
  __shared__ __align__(16) char smem[35840];
  int tid = threadIdx.x, bid = blockIdx.x;

  if (bid > 0) {
    // ---------------- pairs unit u = bid-1 ----------------
    float4* sb = (float4*)smem;               // [4][64]
    float*  sa = (float*)(smem + 4096);       // [4][64]
    int u = bid - 1;
    int cbq = 0;                              // largest c with 2c(c+1) <= u
    while (2 * (cbq + 1) * (cbq + 2) <= u) ++cbq;
    int rb = u - 2 * cbq * (cbq + 1);
    int lane = tid & 63, cq = tid >> 6;
    int cb = cbq * 4 + cq;
    int j0 = cb * 64;
    sb[cq * 64 + lane] = bs[j0 + lane];
    sa[cq * 64 + lane] = area[j0 + lane];
    int i = rb * 64 + lane;
    float4 r = bs[i];
    float ai = area[i];
    __syncthreads();
    if (cb >= rb && ai >= 0.0f) {             // invalid i never pairs
      ull bits = 0;
      for (int c = 0; c < 64; ++c) {
        if ((j0 + c) > i && sa[cq * 64 + c] >= 0.0f &&
            iou_gt_thr(r, ai, sb[cq * 64 + c], sa[cq * 64 + c]))
          bits |= 1ull << c;
      }
      int n = (int)__popcll(bits);
      if (n) {
        if (cb == rb) {                       // in-word pairs
          int base = atomicAdd(&inCnt[cb], n);
          if (base + n > ICAP) {
            __hip_atomic_store(&ctrl[48], 1, __ATOMIC_RELAXED,
                               __HIP_MEMORY_SCOPE_AGENT);
          } else {
            int k = base;
            while (bits) {
              int c = (int)__builtin_ctzll(bits); bits &= bits - 1;
              __hip_atomic_store(&inBuf[cb * ICAP + k++],
                                 ((unsigned)c << 8) | (unsigned)lane,
                                 __ATOMIC_RELAXED, __HIP_MEMORY_SCOPE_AGENT);
            }
          }
        } else {                              // cross-word pairs
          int base = atomicAdd(&ctrl[cb], n);
          if (base + n > CCAP) {
            __hip_atomic_store(&ctrl[48], 1, __ATOMIC_RELAXED,
                               __HIP_MEMORY_SCOPE_AGENT);
          } else {
            int k = base;
            while (bits) {
              int c = (int)__builtin_ctzll(bits); bits &= bits - 1;
              __hip_atomic_store(&crossBuf[cb * CCAP + k++],
                                 ((unsigned)c << 16) | (unsigned)i,
                                 __ATOMIC_RELAXED, __HIP_MEMORY_SCOPE_AGENT);
            }
          }
        }
      }
    }
    __syncthreads();                          // drain all waves' stores
    if (tid == 0)
      __hip_atomic_fetch_add(&ctrl[49], 1, __ATOMIC_RELEASE,
                             __HIP_MEMORY_SCOPE_AGENT);
    return;
  }

  // ---------------- scan (block 0) ----------------
  unsigned (*sCross)[CCAP] = (unsigned(*)[CCAP])(smem + 0);      // 24 KiB
  unsigned (*sIn)[ICAP]    = (unsigned(*)[ICAP])(smem + 24576);  // 3 KiB
  int*  sCCnt     = (int*)(smem + 27648);
  int*  sICnt     = (int*)(smem + 27840);
  ull*  sKeptBits = (ull*)(smem + 28032);
  ull*  sRemv     = (ull*)(smem + 29056);
  u16*  sKeptList = (u16*)(smem + 30080);      // 4000 B
  float4* sWB     = (float4*)(smem + 34080);
  float*  sWA     = (float*)(smem + 35104);
  ull*  sSupW     = (ull*)(smem + 35360);
  int*  sCtl      = (int*)(smem + 35368);      // [0]=base [1]=stop [2]=over

  // pre-spin: sRemv from area sign (K1 output via kernel boundary — proven)
  {
    int wave = tid >> 6, lane = tid & 63;
    for (int w = wave; w < NWORDS; w += 4) {
      float a = area[w * 64 + lane];
      ull inv = __ballot(a < 0.0f);
      if (lane == 0) sRemv[w] = inv;
    }
  }
  if (tid < NWORDS) sKeptBits[tid] = 0ull;
  if (tid == 254) sCtl[0] = 0;
  if (tid == 253) sCtl[1] = 0;

  // wait for all pairs blocks
  if (tid == 0) {
    while (__hip_atomic_load(&ctrl[49], __ATOMIC_ACQUIRE,
                             __HIP_MEMORY_SCOPE_AGENT) < NUNITS)
      __builtin_amdgcn_s_sleep(2);
  }
  __syncthreads();

  // pair payload via agent atomic loads (bypass local caches -> fresh)
  if (tid < MASKW) { sCCnt[tid] = aloadi(&ctrl[tid]); sICnt[tid] = aloadi(&inCnt[tid]); }
  if (tid == 255) sCtl[2] = aloadi(&ctrl[48]);
  for (int k = tid; k < MASKW * CCAP; k += 256)
    ((unsigned*)sCross)[k] = aload(&crossBuf[k]);
  for (int k = tid; k < MASKW * ICAP; k += 256)
    ((unsigned*)sIn)[k] = aload(&inBuf[k]);
  __syncthreads();

  int sOver = sCtl[2];
  // ---- sparse masked phase (wave 0 only)
  if (!sOver && tid < 64) {
    int lane = tid;
    int base = 0;
    for (int w = 0; w < MASKW; ++w) {
      ull avail = ~sRemv[w];
      int cnC = sCCnt[w];
      if (cnC > 0) {                           // lane-parallel cross pairs
        ull csup = 0;
        for (int k = lane; k < cnC; k += 64) {
          unsigned p = sCross[w][k];
          int ii = (int)(p & 0xFFFFu);
          int jl = (int)(p >> 16) & 63;
          if ((sKeptBits[ii >> 6] >> (ii & 63)) & 1ull) csup |= 1ull << jl;
        }
        csup = wave_or64(csup);
        avail &= ~csup;
      }
      int cnI = sICnt[w];
      ull kept;
      if (cnI == 0) {
        kept = avail;
      } else {
        ull dgT = 0ull;                        // my in-word suppressors
        for (int k = 0; k < cnI; ++k) {
          unsigned p = sIn[w][k];              // uniform LDS read
          int il = (int)(p & 63u);
          int jl = (int)(p >> 8) & 63;
          if (lane == jl) dgT |= 1ull << il;
        }
        ull cf = __ballot(((dgT & avail) != 0ull) && ((avail >> lane) & 1ull));
        if (cf == 0ull) {
          kept = avail;
        } else {
          kept = avail;
          while (true) {                       // fixpoint == greedy
            bool sup = (dgT & kept) != 0ull;
            ull kn = avail & ~__ballot(sup);
            if (kn == kept) break;
            kept = kn;
          }
        }
      }
      if (lane == 0) sKeptBits[w] = kept;      // same-wave order: ok
      if ((kept >> lane) & 1ull) {
        int rank = base + (int)__popcll(kept & ((1ull << lane) - 1ull));
        if (rank < NPOST) sKeptList[rank] = (u16)(w * 64 + lane);
      }
      base += (int)__popcll(kept);
      if (base >= NPOST) break;                // ranks >=2000 never emitted
    }
    if (lane == 0) { sCtl[0] = base; if (base >= NPOST) sCtl[1] = 1; }
  }
  __syncthreads();

  // ---- dense fallback (correctness only; not hit by the bench input)
  int startW = sOver ? 0 : MASKW;
  if (!sCtl[1]) {
    for (int w = startW; w < NWORDS; ++w) {
      if (tid < 64) { sWB[tid] = bs[w * 64 + tid]; sWA[tid] = area[w * 64 + tid]; }
      if (tid == 0) *sSupW = sRemv[w];
      __syncthreads();
      int nk = sCtl[0];
      int c = tid & 63;
      for (int k0 = tid >> 6; k0 < nk; k0 += 4) {   // wave per kept box
        int ki = sKeptList[k0];
        float4 kb = bs[ki];                         // uniform load
        bool s = iou_gt_thr(kb, area[ki], sWB[c], sWA[c]);
        ull bits = __ballot(s);
        if (c == 0 && bits) atomicOr(sSupW, bits);
      }
      __syncthreads();
      if (tid < 64) {
        int lane = tid;
        float4 bm = sWB[lane];
        float am = sWA[lane];
        ull dg = 0;
        if (am >= 0.0f) {
          for (int cc = lane + 1; cc < 64; ++cc)
            if (sWA[cc] >= 0.0f && iou_gt_thr(bm, am, sWB[cc], sWA[cc]))
              dg |= 1ull << cc;
        }
        ull avail = ~*sSupW;
        ull kept = resolve_word(dg, avail, lane);
        int base = sCtl[0];
        if ((kept >> lane) & 1ull) {
          int rank = base + (int)__popcll(kept & ((1ull << lane) - 1ull));
          if (rank < NPOST) sKeptList[rank] = (u16)(w * 64 + lane);
        }
        if (lane == 0) {
          int nb = base + (int)__popcll(kept);
          sCtl[0] = nb;
          if (nb >= NPOST) sCtl[1] = 1;
        }
      }
      __syncthreads();
      if (sCtl[1]) break;
    }
  }

  __syncthreads();
  int total = sCtl[0];
  if (total > NPOST) total = NPOST;
  for (int r = tid; r < NPOST; r += 256) {
    float4 v = make_float4(0.0f, 0.0f, 0.0f, 0.0f);
    if (r < total) v = bs[sKeptList[r]];
    reinterpret_cast<float4*>(out)[r] = v;
  }
  // beacon: self-diagnose a repeat failure (never fires on a healthy run)
  if (total == 0 && tid == 0)
    out[0] = 5.0e9f + (float)sCtl[2] * 1.0e8f;
}

// ---------------------------------------------------------------------------
extern "C" void kernel_launch(void* const* d_in, const int* in_sizes, int n_in,
                              void* d_out, int out_size, void* d_ws, size_t ws_size,
                              hipStream_t stream) {
  const float* locs   = (const float*)d_in[0];   // (8192,4) cy,cx,h,w
  const float* scores = (const float*)d_in[1];   // (8192,)

  char* ws = (char*)d_ws;
  float4*   bs       = (float4*)(ws + 0);
  float*    area     = (float*)(ws + 131072);
  int*      ctrl     = (int*)(ws + 163840);
  int*      inCnt    = (int*)(ws + 164096);
  unsigned* crossBuf = (unsigned*)(ws + 164352);
  unsigned* inBuf    = (unsigned*)(ws + 188928);

  rankgather_kernel<<<N / 32, 256, 0, stream>>>(locs, scores, bs, area, ctrl, inCnt);
  pairscan_kernel<<<NUNITS + 1, 256, 0, stream>>>(
      bs, area, ctrl, inCnt, crossBuf, inBuf, (float*)d_out);
}

// Round 13
// 92.986 us; speedup vs baseline: 1.7474x; 1.0203x over previous
//
#include <hip/hip_runtime.h>
#include <cstdint>
#include <cstddef>

typedef unsigned long long ull;
typedef unsigned short u16;

#define N 8192
#define NWORDS 128          // 8192 / 64
#define NPOST 2000
#define NMS_THR 0.7f
#define MASKW 48            // words covered by sparse conflict pairs (stop ~34)
#define CCAP 128            // cross-word pair cap per word
#define ICAP 16             // in-word pair cap per word
#define NUNITS 312          // pair units: sum_{cbq<12} (4cbq+4) = 312

// ---------------- ws layout ----------------
// 0      : bs       float4[8192]  128 KiB (sorted clipped boxes)
// 131072 : area     f32[8192]     32 KiB  (-1.0 marks invalid box)
// 163840 : ctrl     i32[64]       ([0..47] crossCnt, [48] overflow, [49] done)
// 164096 : inCnt    i32[64]
// 164352 : crossBuf u32[48*128]   24 KiB
// 188928 : inBuf    u32[48*16]    3 KiB

// ---------------------------------------------------------------------------
__device__ __forceinline__ float4 decode_clip_box(const float4 L, bool* valid) {
#pragma clang fp contract(off)
  float cy = L.x, cx = L.y, h = L.z, w = L.w;
  float y1 = cy - 0.5f * h;
  float x1 = cx - 0.5f * w;
  float y2 = cy + 0.5f * h;
  float x2 = cx + 0.5f * w;
  *valid = ((y2 - y1) > 16.0f) && ((x2 - x1) > 16.0f);
  float4 b;
  b.x = fminf(fmaxf(y1, 0.0f), 800.0f);
  b.y = fminf(fmaxf(x1, 0.0f), 800.0f);
  b.z = fminf(fmaxf(y2, 0.0f), 800.0f);
  b.w = fminf(fmaxf(x2, 0.0f), 800.0f);
  return b;
}

__device__ __forceinline__ float box_area(const float4 b) {
#pragma clang fp contract(off)
  return (b.z - b.x) * (b.w - b.y);   // clipped => always >= 0
}

__device__ __forceinline__ bool iou_gt_thr(const float4 a, float aa,
                                           const float4 b, float ab) {
#pragma clang fp contract(off)
  float iy = fminf(a.z, b.z) - fmaxf(a.x, b.x);
  float ix = fminf(a.w, b.w) - fmaxf(a.y, b.y);
  iy = fmaxf(iy, 0.0f);
  ix = fmaxf(ix, 0.0f);
  float inter = iy * ix;
  float uni = aa + ab - inter;
  // exact IEEE division: predicate must bit-match the numpy reference
  return (inter > 0.0f) && (uni > 0.0f) && ((inter / uni) > NMS_THR);
}

__device__ __forceinline__ ull wave_or64(ull v) {
  #pragma unroll
  for (int m = 1; m < 64; m <<= 1) {
    unsigned lo = __shfl_xor((unsigned)v, m, 64);
    unsigned hi = __shfl_xor((unsigned)(v >> 32), m, 64);
    v |= ((ull)hi << 32) | (ull)lo;
  }
  return v;
}

// Greedy within-word resolve (fallback path).
__device__ __forceinline__ ull resolve_word(ull dg, ull avail, int lane) {
  ull conflict = __ballot(((dg & avail) != 0ull) && ((avail >> lane) & 1ull));
  if (conflict == 0ull) return avail;
  ull dgT = 0ull;
  #pragma unroll
  for (int c = 0; c < 64; ++c) {
    ull tb = __ballot((dg >> c) & 1ull);
    if (lane == c) dgT = tb;
  }
  ull kept = avail;
  while (true) {                 // fixpoint == greedy (prefix-stabilization)
    bool sup = (dgT & kept) != 0ull;
    ull kn = avail & ~__ballot(sup);
    if (kn == kept) break;
    kept = kn;
  }
  return kept;
}

// Agent-scope relaxed atomics: bypass the XCD-local L1/L2 (read/write at the
// LLC coherence point) WITHOUT the L2 writeback/invalidate that RELEASE/
// ACQUIRE fences impose on this non-coherent-L2 chip.
__device__ __forceinline__ unsigned aload(const unsigned* p) {
  return __hip_atomic_load(p, __ATOMIC_RELAXED, __HIP_MEMORY_SCOPE_AGENT);
}
__device__ __forceinline__ int aloadi(const int* p) {
  return __hip_atomic_load(p, __ATOMIC_RELAXED, __HIP_MEMORY_SCOPE_AGENT);
}

// ===========================================================================
// K1: rank + gather, fused.  GRID = N/32 = 256 blocks.  Block b owns boxes
// b*32..b*32+31; all 8192 decoded scores staged in LDS; thread t computes
// partial rank of box (t&31) over slice (t>>5).  area = -1 marks invalid.
// Block 0 zeroes K2's counters (kernel-boundary visibility -> poison-proof).
// ===========================================================================
__global__ __launch_bounds__(256) void rankgather_kernel(
    const float* __restrict__ locs, const float* __restrict__ scores,
    float4* __restrict__ bs, float* __restrict__ area,
    int* __restrict__ ctrl, int* __restrict__ inCnt) {
  __shared__ float ssc[N];            // 32 KiB decoded scores (-inf invalid)
  __shared__ int sRank[32][9];        // +1 pad: conflict-free
  int tid = threadIdx.x, bid = blockIdx.x;
  if (bid == 0) {
    if (tid < 64) ctrl[tid] = 0;
    else if (tid < 128) inCnt[tid - 64] = 0;
  }
  const float4* locs4 = (const float4*)locs;
  for (int k = 0; k < 32; ++k) {
    int j = k * 256 + tid;            // coalesced
    bool v; (void)decode_clip_box(locs4[j], &v);
    ssc[j] = v ? scores[j] : -__builtin_inff();
  }
  __syncthreads();
  int boxOff = tid & 31;
  int part = tid >> 5;                // 8 slices of 1024
  int i = bid * 32 + boxOff;
  float si = ssc[i];
  const float4* s4 = (const float4*)(ssc + part * 1024);
  int j0 = part * 1024;
  int cnt = 0;
  // j precedes i <=> s_j > s_i || (s_j == s_i && j < i)  (stable descending)
  for (int q = 0; q < 256; ++q) {
    float4 v = s4[q];                 // 2 uniform addrs/wave: 2-way (free)
    int j = j0 + 4 * q;
    cnt += (v.x > si) || ((v.x == si) & ((j + 0) < i));
    cnt += (v.y > si) || ((v.y == si) & ((j + 1) < i));
    cnt += (v.z > si) || ((v.z == si) & ((j + 2) < i));
    cnt += (v.w > si) || ((v.w == si) & ((j + 3) < i));
  }
  sRank[boxOff][part] = cnt;
  __syncthreads();
  if (tid < 32) {
    int r = 0;
    #pragma unroll
    for (int p = 0; p < 8; ++p) r += sRank[tid][p];
    int ig = bid * 32 + tid;
    bool v;
    float4 b = decode_clip_box(locs4[ig], &v);
    bs[r] = b;
    area[r] = v ? box_area(b) : -1.0f;   // sign encodes validity
  }
}

// ===========================================================================
// K2: pairs (blocks 1..312) + scan (block 0), single dispatch.
// Handoff (all RELAXED — no L2 writeback/invalidate storms):
//   producers: agent atomic stores (write-through, acked at LLC) ... then
//   __syncthreads (compiler drains vmcnt(0) before s_barrier => stores
//   globally visible) ... then relaxed fetch_add on the done counter.
//   consumer: relaxed agent spin + relaxed agent payload loads (read LLC).
// No deadlock: only the consumer waits; all 313 blocks co-resident (2/CU max).
// ===========================================================================
__global__ __launch_bounds__(256) void pairscan_kernel(
    const float4* __restrict__ bs, const float* __restrict__ area,
    int* __restrict__ ctrl, int* __restrict__ inCnt,
    unsigned* __restrict__ crossBuf, unsigned* __restrict__ inBuf,
    float* __restrict__ out) {
  __shared__ __align__(16) char smem[35840];
  int tid = threadIdx.x, bid = blockIdx.x;

  if (bid > 0) {
    // ---------------- pairs unit u = bid-1 ----------------
    float4* sb = (float4*)smem;               // [4][64]
    float*  sa = (float*)(smem + 4096);       // [4][64]
    int u = bid - 1;
    int cbq = 0;                              // largest c with 2c(c+1) <= u
    while (2 * (cbq + 1) * (cbq + 2) <= u) ++cbq;
    int rb = u - 2 * cbq * (cbq + 1);
    int lane = tid & 63, cq = tid >> 6;
    int cb = cbq * 4 + cq;
    int j0 = cb * 64;
    sb[cq * 64 + lane] = bs[j0 + lane];
    sa[cq * 64 + lane] = area[j0 + lane];
    int i = rb * 64 + lane;
    float4 r = bs[i];
    float ai = area[i];
    __syncthreads();
    if (cb >= rb && ai >= 0.0f) {             // invalid i never pairs
      ull bits = 0;
      for (int c = 0; c < 64; ++c) {
        if ((j0 + c) > i && sa[cq * 64 + c] >= 0.0f &&
            iou_gt_thr(r, ai, sb[cq * 64 + c], sa[cq * 64 + c]))
          bits |= 1ull << c;
      }
      int n = (int)__popcll(bits);
      if (n) {
        if (cb == rb) {                       // in-word pairs
          int base = atomicAdd(&inCnt[cb], n);
          if (base + n > ICAP) {
            __hip_atomic_store(&ctrl[48], 1, __ATOMIC_RELAXED,
                               __HIP_MEMORY_SCOPE_AGENT);
          } else {
            int k = base;
            while (bits) {
              int c = (int)__builtin_ctzll(bits); bits &= bits - 1;
              __hip_atomic_store(&inBuf[cb * ICAP + k++],
                                 ((unsigned)c << 8) | (unsigned)lane,
                                 __ATOMIC_RELAXED, __HIP_MEMORY_SCOPE_AGENT);
            }
          }
        } else {                              // cross-word pairs
          int base = atomicAdd(&ctrl[cb], n);
          if (base + n > CCAP) {
            __hip_atomic_store(&ctrl[48], 1, __ATOMIC_RELAXED,
                               __HIP_MEMORY_SCOPE_AGENT);
          } else {
            int k = base;
            while (bits) {
              int c = (int)__builtin_ctzll(bits); bits &= bits - 1;
              __hip_atomic_store(&crossBuf[cb * CCAP + k++],
                                 ((unsigned)c << 16) | (unsigned)i,
                                 __ATOMIC_RELAXED, __HIP_MEMORY_SCOPE_AGENT);
            }
          }
        }
      }
    }
    __syncthreads();   // drains vmcnt(0): payload stores acked at LLC here
    if (tid == 0)
      __hip_atomic_fetch_add(&ctrl[49], 1, __ATOMIC_RELAXED,
                             __HIP_MEMORY_SCOPE_AGENT);
    return;
  }

  // ---------------- scan (block 0) ----------------
  unsigned (*sCross)[CCAP] = (unsigned(*)[CCAP])(smem + 0);      // 24 KiB
  unsigned (*sIn)[ICAP]    = (unsigned(*)[ICAP])(smem + 24576);  // 3 KiB
  int*  sCCnt     = (int*)(smem + 27648);
  int*  sICnt     = (int*)(smem + 27840);
  ull*  sKeptBits = (ull*)(smem + 28032);
  ull*  sRemv     = (ull*)(smem + 29056);
  u16*  sKeptList = (u16*)(smem + 30080);      // 4000 B
  float4* sWB     = (float4*)(smem + 34080);
  float*  sWA     = (float*)(smem + 35104);
  ull*  sSupW     = (ull*)(smem + 35360);
  int*  sCtl      = (int*)(smem + 35368);      // [0]=base [1]=stop [2]=over

  // pre-spin: sRemv from area sign (K1 output via kernel boundary — proven)
  {
    int wave = tid >> 6, lane = tid & 63;
    for (int w = wave; w < NWORDS; w += 4) {
      float a = area[w * 64 + lane];
      ull inv = __ballot(a < 0.0f);
      if (lane == 0) sRemv[w] = inv;
    }
  }
  if (tid < NWORDS) sKeptBits[tid] = 0ull;
  if (tid == 254) sCtl[0] = 0;
  if (tid == 253) sCtl[1] = 0;

  // wait for all pairs blocks (relaxed agent poll: reads LLC, no invalidates)
  if (tid == 0) {
    while (__hip_atomic_load(&ctrl[49], __ATOMIC_RELAXED,
                             __HIP_MEMORY_SCOPE_AGENT) < NUNITS)
      __builtin_amdgcn_s_sleep(2);
  }
  __syncthreads();

  // pair payload via relaxed agent atomic loads (bypass local caches)
  if (tid < MASKW) { sCCnt[tid] = aloadi(&ctrl[tid]); sICnt[tid] = aloadi(&inCnt[tid]); }
  if (tid == 255) sCtl[2] = aloadi(&ctrl[48]);
  for (int k = tid; k < MASKW * CCAP; k += 256)
    ((unsigned*)sCross)[k] = aload(&crossBuf[k]);
  for (int k = tid; k < MASKW * ICAP; k += 256)
    ((unsigned*)sIn)[k] = aload(&inBuf[k]);
  __syncthreads();

  int sOver = sCtl[2];
  // ---- sparse masked phase (wave 0 only)
  if (!sOver && tid < 64) {
    int lane = tid;
    int base = 0;
    for (int w = 0; w < MASKW; ++w) {
      ull avail = ~sRemv[w];
      int cnC = sCCnt[w];
      if (cnC > 0) {                           // lane-parallel cross pairs
        ull csup = 0;
        for (int k = lane; k < cnC; k += 64) {
          unsigned p = sCross[w][k];
          int ii = (int)(p & 0xFFFFu);
          int jl = (int)(p >> 16) & 63;
          if ((sKeptBits[ii >> 6] >> (ii & 63)) & 1ull) csup |= 1ull << jl;
        }
        csup = wave_or64(csup);
        avail &= ~csup;
      }
      int cnI = sICnt[w];
      ull kept;
      if (cnI == 0) {
        kept = avail;
      } else {
        ull dgT = 0ull;                        // my in-word suppressors
        for (int k = 0; k < cnI; ++k) {
          unsigned p = sIn[w][k];              // uniform LDS read
          int il = (int)(p & 63u);
          int jl = (int)(p >> 8) & 63;
          if (lane == jl) dgT |= 1ull << il;
        }
        ull cf = __ballot(((dgT & avail) != 0ull) && ((avail >> lane) & 1ull));
        if (cf == 0ull) {
          kept = avail;
        } else {
          kept = avail;
          while (true) {                       // fixpoint == greedy
            bool sup = (dgT & kept) != 0ull;
            ull kn = avail & ~__ballot(sup);
            if (kn == kept) break;
            kept = kn;
          }
        }
      }
      if (lane == 0) sKeptBits[w] = kept;      // same-wave order: ok
      if ((kept >> lane) & 1ull) {
        int rank = base + (int)__popcll(kept & ((1ull << lane) - 1ull));
        if (rank < NPOST) sKeptList[rank] = (u16)(w * 64 + lane);
      }
      base += (int)__popcll(kept);
      if (base >= NPOST) break;                // ranks >=2000 never emitted
    }
    if (lane == 0) { sCtl[0] = base; if (base >= NPOST) sCtl[1] = 1; }
  }
  __syncthreads();

  // ---- dense fallback (correctness only; not hit by the bench input)
  int startW = sOver ? 0 : MASKW;
  if (!sCtl[1]) {
    for (int w = startW; w < NWORDS; ++w) {
      if (tid < 64) { sWB[tid] = bs[w * 64 + tid]; sWA[tid] = area[w * 64 + tid]; }
      if (tid == 0) *sSupW = sRemv[w];
      __syncthreads();
      int nk = sCtl[0];
      int c = tid & 63;
      for (int k0 = tid >> 6; k0 < nk; k0 += 4) {   // wave per kept box
        int ki = sKeptList[k0];
        float4 kb = bs[ki];                         // uniform load
        bool s = iou_gt_thr(kb, area[ki], sWB[c], sWA[c]);
        ull bits = __ballot(s);
        if (c == 0 && bits) atomicOr(sSupW, bits);
      }
      __syncthreads();
      if (tid < 64) {
        int lane = tid;
        float4 bm = sWB[lane];
        float am = sWA[lane];
        ull dg = 0;
        if (am >= 0.0f) {
          for (int cc = lane + 1; cc < 64; ++cc)
            if (sWA[cc] >= 0.0f && iou_gt_thr(bm, am, sWB[cc], sWA[cc]))
              dg |= 1ull << cc;
        }
        ull avail = ~*sSupW;
        ull kept = resolve_word(dg, avail, lane);
        int base = sCtl[0];
        if ((kept >> lane) & 1ull) {
          int rank = base + (int)__popcll(kept & ((1ull << lane) - 1ull));
          if (rank < NPOST) sKeptList[rank] = (u16)(w * 64 + lane);
        }
        if (lane == 0) {
          int nb = base + (int)__popcll(kept);
          sCtl[0] = nb;
          if (nb >= NPOST) sCtl[1] = 1;
        }
      }
      __syncthreads();
      if (sCtl[1]) break;
    }
  }

  __syncthreads();
  int total = sCtl[0];
  if (total > NPOST) total = NPOST;
  for (int r = tid; r < NPOST; r += 256) {
    float4 v = make_float4(0.0f, 0.0f, 0.0f, 0.0f);
    if (r < total) v = bs[sKeptList[r]];
    reinterpret_cast<float4*>(out)[r] = v;
  }
  // beacon: self-diagnose a repeat failure (never fires on a healthy run)
  if (total == 0 && tid == 0)
    out[0] = 5.0e9f + (float)sCtl[2] * 1.0e8f;
}

// ---------------------------------------------------------------------------
extern "C" void kernel_launch(void* const* d_in, const int* in_sizes, int n_in,
                              void* d_out, int out_size, void* d_ws, size_t ws_size,
                              hipStream_t stream) {
  const float* locs   = (const float*)d_in[0];   // (8192,4) cy,cx,h,w
  const float* scores = (const float*)d_in[1];   // (8192,)

  char* ws = (char*)d_ws;
  float4*   bs       = (float4*)(ws + 0);
  float*    area     = (float*)(ws + 131072);
  int*      ctrl     = (int*)(ws + 163840);
  int*      inCnt    = (int*)(ws + 164096);
  unsigned* crossBuf = (unsigned*)(ws + 164352);
  unsigned* inBuf    = (unsigned*)(ws + 188928);

  rankgather_kernel<<<N / 32, 256, 0, stream>>>(locs, scores, bs, area, ctrl, inCnt);
  pairscan_kernel<<<NUNITS + 1, 256, 0, stream>>>(
      bs, area, ctrl, inCnt, crossBuf, inBuf, (float*)d_out);
}

// Round 16
// 78.870 us; speedup vs baseline: 2.0601x; 1.1790x over previous
//
#include <hip/hip_runtime.h>
#include <cstdint>
#include <cstddef>

typedef unsigned long long ull;
typedef unsigned short u16;

#define N 8192
#define NWORDS 128          // 8192 / 64
#define NPOST 2000
#define NMS_THR 0.7f
#define MASKW 48            // words covered by sparse conflict pairs (stop ~34)
#define SCAP 128            // cross-word pair cap per SOURCE word
#define ICAP 16             // in-word pair cap per word
#define NUNITS 312          // pair units: sum_{cbq<12} 4(cbq+1) = 312

// ---------------- ws layout ----------------
// 0      : bs       float4[8192]  128 KiB (sorted clipped boxes)
// 131072 : area     f32[8192]     32 KiB  (-1.0 marks invalid box)
// 163840 : ctrl     i32[64]       ([0..47] srcCnt, [48] overflow, [49] done)
// 164096 : inCnt    i32[64]
// 164352 : srcBuf   u32[48*128]   24 KiB  ((il<<13)|(wt<<6)|jl, bucket=src word)
// 188928 : inBuf    u32[48*16]    3 KiB   ((jl<<8)|il per in-word pair)

// ---------------------------------------------------------------------------
__device__ __forceinline__ float4 decode_clip_box(const float4 L, bool* valid) {
#pragma clang fp contract(off)
  float cy = L.x, cx = L.y, h = L.z, w = L.w;
  float y1 = cy - 0.5f * h;
  float x1 = cx - 0.5f * w;
  float y2 = cy + 0.5f * h;
  float x2 = cx + 0.5f * w;
  *valid = ((y2 - y1) > 16.0f) && ((x2 - x1) > 16.0f);
  float4 b;
  b.x = fminf(fmaxf(y1, 0.0f), 800.0f);
  b.y = fminf(fmaxf(x1, 0.0f), 800.0f);
  b.z = fminf(fmaxf(y2, 0.0f), 800.0f);
  b.w = fminf(fmaxf(x2, 0.0f), 800.0f);
  return b;
}

__device__ __forceinline__ float box_area(const float4 b) {
#pragma clang fp contract(off)
  return (b.z - b.x) * (b.w - b.y);   // clipped => always >= 0
}

__device__ __forceinline__ bool iou_gt_thr(const float4 a, float aa,
                                           const float4 b, float ab) {
#pragma clang fp contract(off)
  float iy = fminf(a.z, b.z) - fmaxf(a.x, b.x);
  float ix = fminf(a.w, b.w) - fmaxf(a.y, b.y);
  iy = fmaxf(iy, 0.0f);
  ix = fmaxf(ix, 0.0f);
  float inter = iy * ix;
  float uni = aa + ab - inter;
  // exact IEEE division: predicate must bit-match the numpy reference
  return (inter > 0.0f) && (uni > 0.0f) && ((inter / uni) > NMS_THR);
}

// Greedy within-word resolve from dense "who-I-suppress" (fallback only).
__device__ __forceinline__ ull resolve_word(ull dg, ull avail, int lane) {
  ull conflict = __ballot(((dg & avail) != 0ull) && ((avail >> lane) & 1ull));
  if (conflict == 0ull) return avail;
  ull dgT = 0ull;
  #pragma unroll
  for (int c = 0; c < 64; ++c) {
    ull tb = __ballot((dg >> c) & 1ull);
    if (lane == c) dgT = tb;
  }
  ull kept = avail;
  while (true) {                 // fixpoint == greedy (prefix-stabilization)
    bool sup = (dgT & kept) != 0ull;
    ull kn = avail & ~__ballot(sup);
    if (kn == kept) break;
    kept = kn;
  }
  return kept;
}

__device__ __forceinline__ unsigned aload(const unsigned* p) {
  return __hip_atomic_load(p, __ATOMIC_RELAXED, __HIP_MEMORY_SCOPE_AGENT);
}
__device__ __forceinline__ int aloadi(const int* p) {
  return __hip_atomic_load(p, __ATOMIC_RELAXED, __HIP_MEMORY_SCOPE_AGENT);
}

// ===========================================================================
// K1: rank + gather, fused.  GRID = N/32 = 256 blocks (proven r12/r13).
// ===========================================================================
__global__ __launch_bounds__(256) void rankgather_kernel(
    const float* __restrict__ locs, const float* __restrict__ scores,
    float4* __restrict__ bs, float* __restrict__ area,
    int* __restrict__ ctrl, int* __restrict__ inCnt) {
  __shared__ float ssc[N];            // 32 KiB decoded scores (-inf invalid)
  __shared__ int sRank[32][9];        // +1 pad: conflict-free
  int tid = threadIdx.x, bid = blockIdx.x;
  if (bid == 0) {
    if (tid < 64) ctrl[tid] = 0;
    else if (tid < 128) inCnt[tid - 64] = 0;
  }
  const float4* locs4 = (const float4*)locs;
  for (int k = 0; k < 32; ++k) {
    int j = k * 256 + tid;            // coalesced
    bool v; (void)decode_clip_box(locs4[j], &v);
    ssc[j] = v ? scores[j] : -__builtin_inff();
  }
  __syncthreads();
  int boxOff = tid & 31;
  int part = tid >> 5;                // 8 slices of 1024
  int i = bid * 32 + boxOff;
  float si = ssc[i];
  const float4* s4 = (const float4*)(ssc + part * 1024);
  int j0 = part * 1024;
  int cnt = 0;
  // j precedes i <=> s_j > s_i || (s_j == s_i && j < i)  (stable descending)
  for (int q = 0; q < 256; ++q) {
    float4 v = s4[q];
    int j = j0 + 4 * q;
    cnt += (v.x > si) || ((v.x == si) & ((j + 0) < i));
    cnt += (v.y > si) || ((v.y == si) & ((j + 1) < i));
    cnt += (v.z > si) || ((v.z == si) & ((j + 2) < i));
    cnt += (v.w > si) || ((v.w == si) & ((j + 3) < i));
  }
  sRank[boxOff][part] = cnt;
  __syncthreads();
  if (tid < 32) {
    int r = 0;
    #pragma unroll
    for (int p = 0; p < 8; ++p) r += sRank[tid][p];
    int ig = bid * 32 + tid;
    bool v;
    float4 b = decode_clip_box(locs4[ig], &v);
    bs[r] = b;
    area[r] = v ? box_area(b) : -1.0f;   // sign encodes validity
  }
}

// ===========================================================================
// K2: pairs (blocks 1..312) + scan (block 0), single dispatch.
// Cross pairs bucketed by SOURCE word; scan propagates them eagerly after
// resolving each word (lane-parallel LDS atomicOr) — NO cross-lane reduce,
// NO shfl chains in the serial loop.  Handoff = proven r12/r13 mechanism.
// ===========================================================================
__global__ __launch_bounds__(256) void pairscan_kernel(
    const float4* __restrict__ bs, const float* __restrict__ area,
    int* __restrict__ ctrl, int* __restrict__ inCnt,
    unsigned* __restrict__ srcBuf, unsigned* __restrict__ inBuf,
    float* __restrict__ out) {
  __shared__ __align__(16) char smem[35840];
  int tid = threadIdx.x, bid = blockIdx.x;

  if (bid > 0) {
    // ---------------- pairs unit u = bid-1 ----------------
    float4* sb = (float4*)smem;               // [4][64]
    float*  sa = (float*)(smem + 4096);       // [4][64]
    int u = bid - 1;
    int cbq = 0;                              // largest c with 2c(c+1) <= u
    while (2 * (cbq + 1) * (cbq + 2) <= u) ++cbq;
    int rb = u - 2 * cbq * (cbq + 1);
    int lane = tid & 63, cq = tid >> 6;
    int cb = cbq * 4 + cq;
    int j0 = cb * 64;
    sb[cq * 64 + lane] = bs[j0 + lane];
    sa[cq * 64 + lane] = area[j0 + lane];
    int i = rb * 64 + lane;
    float4 r = bs[i];
    float ai = area[i];
    __syncthreads();
    if (cb >= rb && ai >= 0.0f) {             // invalid i never pairs
      ull bits = 0;
      for (int c = 0; c < 64; ++c) {
        if ((j0 + c) > i && sa[cq * 64 + c] >= 0.0f &&
            iou_gt_thr(r, ai, sb[cq * 64 + c], sa[cq * 64 + c]))
          bits |= 1ull << c;
      }
      int n = (int)__popcll(bits);
      if (n) {
        if (cb == rb) {                       // in-word pairs (bucket = word)
          int base = atomicAdd(&inCnt[cb], n);
          if (base + n > ICAP) {
            __hip_atomic_store(&ctrl[48], 1, __ATOMIC_RELAXED,
                               __HIP_MEMORY_SCOPE_AGENT);
          } else {
            int k = base;
            while (bits) {
              int c = (int)__builtin_ctzll(bits); bits &= bits - 1;
              __hip_atomic_store(&inBuf[cb * ICAP + k++],
                                 ((unsigned)c << 8) | (unsigned)lane,
                                 __ATOMIC_RELAXED, __HIP_MEMORY_SCOPE_AGENT);
            }
          }
        } else {                              // cross pairs, bucket = SOURCE rb
          int base = atomicAdd(&ctrl[rb], n);
          if (base + n > SCAP) {
            __hip_atomic_store(&ctrl[48], 1, __ATOMIC_RELAXED,
                               __HIP_MEMORY_SCOPE_AGENT);
          } else {
            int k = base;
            while (bits) {
              int c = (int)__builtin_ctzll(bits); bits &= bits - 1;
              // (il<<13) | (wt<<6) | jl
              __hip_atomic_store(&srcBuf[rb * SCAP + k++],
                                 ((unsigned)lane << 13) | ((unsigned)cb << 6) |
                                     (unsigned)c,
                                 __ATOMIC_RELAXED, __HIP_MEMORY_SCOPE_AGENT);
            }
          }
        }
      }
    }
    __syncthreads();   // drains vmcnt(0): payload stores acked at LLC here
    if (tid == 0)
      __hip_atomic_fetch_add(&ctrl[49], 1, __ATOMIC_RELAXED,
                             __HIP_MEMORY_SCOPE_AGENT);
    return;
  }

  // ---------------- scan (block 0) ----------------
  unsigned (*sSrc)[SCAP] = (unsigned(*)[SCAP])(smem + 0);       // 24 KiB
  unsigned (*sIn)[ICAP]  = (unsigned(*)[ICAP])(smem + 24576);   // 3 KiB
  int*  sSCnt     = (int*)(smem + 27648);
  int*  sICnt     = (int*)(smem + 27840);
  ull*  sRemv     = (ull*)(smem + 28032);      // 1 KiB
  u16*  sKeptList = (u16*)(smem + 29056);      // 4000 B
  float4* sWB     = (float4*)(smem + 33056);
  float*  sWA     = (float*)(smem + 34080);
  ull*  sSupW     = (ull*)(smem + 34336);
  int*  sCtl      = (int*)(smem + 34344);      // [0]=base [1]=stop [2]=over

  // pre-spin: sRemv from area sign (K1 output via kernel boundary — proven)
  {
    int wave = tid >> 6, lane = tid & 63;
    for (int w = wave; w < NWORDS; w += 4) {
      float a = area[w * 64 + lane];
      ull inv = __ballot(a < 0.0f);
      if (lane == 0) sRemv[w] = inv;
    }
  }
  if (tid == 254) sCtl[0] = 0;
  if (tid == 253) sCtl[1] = 0;

  // wait for all pairs blocks (relaxed agent poll, proven r12/r13)
  if (tid == 0) {
    while (__hip_atomic_load(&ctrl[49], __ATOMIC_RELAXED,
                             __HIP_MEMORY_SCOPE_AGENT) < NUNITS)
      __builtin_amdgcn_s_sleep(2);
  }
  __syncthreads();

  // payload staging: 4-wide unrolled agent atomic loads (4 in flight)
  if (tid < MASKW) { sSCnt[tid] = aloadi(&ctrl[tid]); sICnt[tid] = aloadi(&inCnt[tid]); }
  if (tid == 255) sCtl[2] = aloadi(&ctrl[48]);
  for (int k = tid * 4; k < MASKW * SCAP; k += 1024) {
    unsigned a0 = aload(&srcBuf[k + 0]);
    unsigned a1 = aload(&srcBuf[k + 1]);
    unsigned a2 = aload(&srcBuf[k + 2]);
    unsigned a3 = aload(&srcBuf[k + 3]);
    ((unsigned*)sSrc)[k + 0] = a0;
    ((unsigned*)sSrc)[k + 1] = a1;
    ((unsigned*)sSrc)[k + 2] = a2;
    ((unsigned*)sSrc)[k + 3] = a3;
  }
  for (int k = tid; k < MASKW * ICAP; k += 256)
    ((unsigned*)sIn)[k] = aload(&inBuf[k]);
  __syncthreads();

  int sOver = sCtl[2];
  // ---- sparse masked phase (wave 0 only; no shfl/reduce in the loop)
  if (!sOver && tid < 64) {
    int lane = tid;
    int base = 0;
    for (int w = 0; w < MASKW; ++w) {
      ull avail = ~sRemv[w];                   // in-order LDS: sees all OrS
      int cnI = sICnt[w];
      ull kept;
      if (cnI == 0) {
        kept = avail;
      } else {
        ull dgT = 0ull;                        // my in-word suppressors
        for (int k = 0; k < cnI; ++k) {
          unsigned p = sIn[w][k];              // uniform LDS read
          int il = (int)(p & 63u);
          int jl = (int)(p >> 8) & 63;
          if (lane == jl) dgT |= 1ull << il;
        }
        ull cf = __ballot(((dgT & avail) != 0ull) && ((avail >> lane) & 1ull));
        if (cf == 0ull) {
          kept = avail;
        } else {
          kept = avail;
          while (true) {                       // fixpoint == greedy
            bool sup = (dgT & kept) != 0ull;
            ull kn = avail & ~__ballot(sup);
            if (kn == kept) break;
            kept = kn;
          }
        }
      }
      if ((kept >> lane) & 1ull) {
        int rank = base + (int)__popcll(kept & ((1ull << lane) - 1ull));
        if (rank < NPOST) sKeptList[rank] = (u16)(w * 64 + lane);
      }
      base += (int)__popcll(kept);
      if (base >= NPOST) break;                // ranks >=2000 never emitted
      // eager push-forward: lane-parallel, no reduction
      int cnS = sSCnt[w];
      for (int k = lane; k < cnS; k += 64) {
        unsigned p = sSrc[w][k];
        int il = (int)(p >> 13) & 63;
        if ((kept >> il) & 1ull) {
          int wt = (int)(p >> 6) & 127;
          atomicOr(&sRemv[wt], 1ull << (p & 63u));   // LDS atomic
        }
      }
    }
    if (lane == 0) { sCtl[0] = base; if (base >= NPOST) sCtl[1] = 1; }
  }
  __syncthreads();

  // ---- dense fallback (correctness only; not hit by the bench input)
  int startW = sOver ? 0 : MASKW;
  if (!sCtl[1]) {
    for (int w = startW; w < NWORDS; ++w) {
      if (tid < 64) { sWB[tid] = bs[w * 64 + tid]; sWA[tid] = area[w * 64 + tid]; }
      if (tid == 0) *sSupW = sRemv[w];
      __syncthreads();
      int nk = sCtl[0];
      int c = tid & 63;
      for (int k0 = tid >> 6; k0 < nk; k0 += 4) {   // wave per kept box
        int ki = sKeptList[k0];
        float4 kb = bs[ki];                         // uniform load
        bool s = iou_gt_thr(kb, area[ki], sWB[c], sWA[c]);
        ull bits = __ballot(s);
        if (c == 0 && bits) atomicOr(sSupW, bits);
      }
      __syncthreads();
      if (tid < 64) {
        int lane = tid;
        float4 bm = sWB[lane];
        float am = sWA[lane];
        ull dg = 0;
        if (am >= 0.0f) {
          for (int cc = lane + 1; cc < 64; ++cc)
            if (sWA[cc] >= 0.0f && iou_gt_thr(bm, am, sWB[cc], sWA[cc]))
              dg |= 1ull << cc;
        }
        ull avail = ~*sSupW;
        ull kept = resolve_word(dg, avail, lane);
        int base = sCtl[0];
        if ((kept >> lane) & 1ull) {
          int rank = base + (int)__popcll(kept & ((1ull << lane) - 1ull));
          if (rank < NPOST) sKeptList[rank] = (u16)(w * 64 + lane);
        }
        if (lane == 0) {
          int nb = base + (int)__popcll(kept);
          sCtl[0] = nb;
          if (nb >= NPOST) sCtl[1] = 1;
        }
      }
      __syncthreads();
      if (sCtl[1]) break;
    }
  }

  __syncthreads();
  int total = sCtl[0];
  if (total > NPOST) total = NPOST;
  for (int r = tid; r < NPOST; r += 256) {
    float4 v = make_float4(0.0f, 0.0f, 0.0f, 0.0f);
    if (r < total) v = bs[sKeptList[r]];
    reinterpret_cast<float4*>(out)[r] = v;
  }
  // beacon: self-diagnose a repeat failure (never fires on a healthy run)
  if (total == 0 && tid == 0)
    out[0] = 5.0e9f + (float)sCtl[2] * 1.0e8f;
}

// ---------------------------------------------------------------------------
extern "C" void kernel_launch(void* const* d_in, const int* in_sizes, int n_in,
                              void* d_out, int out_size, void* d_ws, size_t ws_size,
                              hipStream_t stream) {
  const float* locs   = (const float*)d_in[0];   // (8192,4) cy,cx,h,w
  const float* scores = (const float*)d_in[1];   // (8192,)

  char* ws = (char*)d_ws;
  float4*   bs       = (float4*)(ws + 0);
  float*    area     = (float*)(ws + 131072);
  int*      ctrl     = (int*)(ws + 163840);
  int*      inCnt    = (int*)(ws + 164096);
  unsigned* srcBuf   = (unsigned*)(ws + 164352);
  unsigned* inBuf    = (unsigned*)(ws + 188928);

  rankgather_kernel<<<N / 32, 256, 0, stream>>>(locs, scores, bs, area, ctrl, inCnt);
  pairscan_kernel<<<NUNITS + 1, 256, 0, stream>>>(
      bs, area, ctrl, inCnt, srcBuf, inBuf, (float*)d_out);
}

// Round 19
// 63.286 us; speedup vs baseline: 2.5674x; 1.2463x over previous
//
#include <hip/hip_runtime.h>
#include <cstdint>
#include <cstddef>

typedef unsigned long long ull;
typedef unsigned short u16;

#define N 8192
#define NWORDS 128          // 8192 / 64
#define NPOST 2000
#define NMS_THR 0.7f
#define MASKW 48            // words covered by sparse conflict pairs (stop ~34)
#define SCAP 128            // cross-word pair cap per SOURCE word
#define ICAP 16             // in-word pair cap per word
#define NUNITS 312          // pair units: sum_{cbq<12} 4(cbq+1) = 312
#define SLICE_STRIDE 260    // floats; 1040B: parts hit disjoint banks

// ---------------- ws layout ----------------
// 0      : bs       float4[8192]  128 KiB (sorted clipped boxes)
// 131072 : area     f32[8192]     32 KiB  (-1.0 marks invalid box)
// 163840 : ctrl     i32[64]       ([0..47] srcCnt, [48] overflow, [49] done)
// 164096 : inCnt    i32[64]
// 164352 : srcBuf   u32[48*128]   24 KiB  ((il<<13)|(wt<<6)|jl, bucket=src word)
// 188928 : inBuf    u32[48*16]    3 KiB   ((jl<<8)|il per in-word pair)

// ---------------------------------------------------------------------------
__device__ __forceinline__ float4 decode_clip_box(const float4 L, bool* valid) {
#pragma clang fp contract(off)
  float cy = L.x, cx = L.y, h = L.z, w = L.w;
  float y1 = cy - 0.5f * h;
  float x1 = cx - 0.5f * w;
  float y2 = cy + 0.5f * h;
  float x2 = cx + 0.5f * w;
  *valid = ((y2 - y1) > 16.0f) && ((x2 - x1) > 16.0f);
  float4 b;
  b.x = fminf(fmaxf(y1, 0.0f), 800.0f);
  b.y = fminf(fmaxf(x1, 0.0f), 800.0f);
  b.z = fminf(fmaxf(y2, 0.0f), 800.0f);
  b.w = fminf(fmaxf(x2, 0.0f), 800.0f);
  return b;
}

__device__ __forceinline__ float box_area(const float4 b) {
#pragma clang fp contract(off)
  return (b.z - b.x) * (b.w - b.y);   // clipped => always >= 0
}

__device__ __forceinline__ bool iou_gt_thr(const float4 a, float aa,
                                           const float4 b, float ab) {
#pragma clang fp contract(off)
  float iy = fminf(a.z, b.z) - fmaxf(a.x, b.x);
  float ix = fminf(a.w, b.w) - fmaxf(a.y, b.y);
  iy = fmaxf(iy, 0.0f);
  ix = fmaxf(ix, 0.0f);
  float inter = iy * ix;
  float uni = aa + ab - inter;
  // exact IEEE division: predicate must bit-match the numpy reference
  return (inter > 0.0f) && (uni > 0.0f) && ((inter / uni) > NMS_THR);
}

// Greedy within-word resolve from dense "who-I-suppress" (fallback only).
__device__ __forceinline__ ull resolve_word(ull dg, ull avail, int lane) {
  ull conflict = __ballot(((dg & avail) != 0ull) && ((avail >> lane) & 1ull));
  if (conflict == 0ull) return avail;
  ull dgT = 0ull;
  #pragma unroll
  for (int c = 0; c < 64; ++c) {
    ull tb = __ballot((dg >> c) & 1ull);
    if (lane == c) dgT = tb;
  }
  ull kept = avail;
  while (true) {                 // fixpoint == greedy (prefix-stabilization)
    bool sup = (dgT & kept) != 0ull;
    ull kn = avail & ~__ballot(sup);
    if (kn == kept) break;
    kept = kn;
  }
  return kept;
}

__device__ __forceinline__ unsigned aload(const unsigned* p) {
  return __hip_atomic_load(p, __ATOMIC_RELAXED, __HIP_MEMORY_SCOPE_AGENT);
}
__device__ __forceinline__ int aloadi(const int* p) {
  return __hip_atomic_load(p, __ATOMIC_RELAXED, __HIP_MEMORY_SCOPE_AGENT);
}

// ===========================================================================
// K1: rank + gather, fused.  GRID = N/8 = 1024 blocks (4 blocks/CU -> 4
// waves/SIMD; r16's grid=256 left 1 wave/SIMD, 43.6us latency-bound).
// Block b owns boxes b*8..b*8+7.  All 8192 decoded scores staged in LDS with
// slice stride 260 floats (parts land on disjoint banks).  Thread t ranks
// box (t&7) over slice (t>>3) (32 slices x 256 scores).  area=-1 = invalid.
// Block 0 zeroes K2's counters (kernel-boundary visibility -> poison-proof).
// ===========================================================================
__global__ __launch_bounds__(256) void rankgather_kernel(
    const float* __restrict__ locs, const float* __restrict__ scores,
    float4* __restrict__ bs, float* __restrict__ area,
    int* __restrict__ ctrl, int* __restrict__ inCnt) {
  __shared__ float ssc[32 * SLICE_STRIDE];   // 33280 B, slices of 256 + pad
  __shared__ int sRank[8][33];               // +1 pad: conflict-free
  int tid = threadIdx.x, bid = blockIdx.x;
  if (bid == 0) {
    if (tid < 64) ctrl[tid] = 0;
    else if (tid < 128) inCnt[tid - 64] = 0;
  }
  const float4* locs4 = (const float4*)locs;
  for (int k = 0; k < 32; ++k) {
    int j = k * 256 + tid;                   // coalesced
    bool v; (void)decode_clip_box(locs4[j], &v);
    float s = v ? scores[j] : -__builtin_inff();
    ssc[(j >> 8) * SLICE_STRIDE + (j & 255)] = s;
  }
  __syncthreads();
  int boxOff = tid & 7;
  int part = tid >> 3;                       // 32 slices of 256 scores
  int i = bid * 8 + boxOff;
  float si = ssc[(i >> 8) * SLICE_STRIDE + (i & 255)];
  const float4* s4 = (const float4*)(ssc + part * SLICE_STRIDE);
  int j0 = part * 256;
  int cnt = 0;
  // j precedes i <=> s_j > s_i || (s_j == s_i && j < i)  (stable descending)
  for (int q = 0; q < 64; ++q) {
    float4 v = s4[q];                        // 8 distinct banksets: no conflict
    int j = j0 + 4 * q;
    cnt += (v.x > si) || ((v.x == si) & ((j + 0) < i));
    cnt += (v.y > si) || ((v.y == si) & ((j + 1) < i));
    cnt += (v.z > si) || ((v.z == si) & ((j + 2) < i));
    cnt += (v.w > si) || ((v.w == si) & ((j + 3) < i));
  }
  sRank[boxOff][part] = cnt;
  __syncthreads();
  if (tid < 8) {
    int r = 0;
    #pragma unroll
    for (int p = 0; p < 32; ++p) r += sRank[tid][p];
    int ig = bid * 8 + tid;
    bool v;
    float4 b = decode_clip_box(locs4[ig], &v);
    bs[r] = b;
    area[r] = v ? box_area(b) : -1.0f;       // sign encodes validity
  }
}

// ===========================================================================
// K2: pairs (blocks 1..312) + scan (block 0), single dispatch.
// Byte-identical to round 16 (passed, 78.9us total).
// ===========================================================================
__global__ __launch_bounds__(256) void pairscan_kernel(
    const float4* __restrict__ bs, const float* __restrict__ area,
    int* __restrict__ ctrl, int* __restrict__ inCnt,
    unsigned* __restrict__ srcBuf, unsigned* __restrict__ inBuf,
    float* __restrict__ out) {
  __shared__ __align__(16) char smem[35840];
  int tid = threadIdx.x, bid = blockIdx.x;

  if (bid > 0) {
    // ---------------- pairs unit u = bid-1 ----------------
    float4* sb = (float4*)smem;               // [4][64]
    float*  sa = (float*)(smem + 4096);       // [4][64]
    int u = bid - 1;
    int cbq = 0;                              // largest c with 2c(c+1) <= u
    while (2 * (cbq + 1) * (cbq + 2) <= u) ++cbq;
    int rb = u - 2 * cbq * (cbq + 1);
    int lane = tid & 63, cq = tid >> 6;
    int cb = cbq * 4 + cq;
    int j0 = cb * 64;
    sb[cq * 64 + lane] = bs[j0 + lane];
    sa[cq * 64 + lane] = area[j0 + lane];
    int i = rb * 64 + lane;
    float4 r = bs[i];
    float ai = area[i];
    __syncthreads();
    if (cb >= rb && ai >= 0.0f) {             // invalid i never pairs
      ull bits = 0;
      for (int c = 0; c < 64; ++c) {
        if ((j0 + c) > i && sa[cq * 64 + c] >= 0.0f &&
            iou_gt_thr(r, ai, sb[cq * 64 + c], sa[cq * 64 + c]))
          bits |= 1ull << c;
      }
      int n = (int)__popcll(bits);
      if (n) {
        if (cb == rb) {                       // in-word pairs (bucket = word)
          int base = atomicAdd(&inCnt[cb], n);
          if (base + n > ICAP) {
            __hip_atomic_store(&ctrl[48], 1, __ATOMIC_RELAXED,
                               __HIP_MEMORY_SCOPE_AGENT);
          } else {
            int k = base;
            while (bits) {
              int c = (int)__builtin_ctzll(bits); bits &= bits - 1;
              __hip_atomic_store(&inBuf[cb * ICAP + k++],
                                 ((unsigned)c << 8) | (unsigned)lane,
                                 __ATOMIC_RELAXED, __HIP_MEMORY_SCOPE_AGENT);
            }
          }
        } else {                              // cross pairs, bucket = SOURCE rb
          int base = atomicAdd(&ctrl[rb], n);
          if (base + n > SCAP) {
            __hip_atomic_store(&ctrl[48], 1, __ATOMIC_RELAXED,
                               __HIP_MEMORY_SCOPE_AGENT);
          } else {
            int k = base;
            while (bits) {
              int c = (int)__builtin_ctzll(bits); bits &= bits - 1;
              // (il<<13) | (wt<<6) | jl
              __hip_atomic_store(&srcBuf[rb * SCAP + k++],
                                 ((unsigned)lane << 13) | ((unsigned)cb << 6) |
                                     (unsigned)c,
                                 __ATOMIC_RELAXED, __HIP_MEMORY_SCOPE_AGENT);
            }
          }
        }
      }
    }
    __syncthreads();   // drains vmcnt(0): payload stores acked at LLC here
    if (tid == 0)
      __hip_atomic_fetch_add(&ctrl[49], 1, __ATOMIC_RELAXED,
                             __HIP_MEMORY_SCOPE_AGENT);
    return;
  }

  // ---------------- scan (block 0) ----------------
  unsigned (*sSrc)[SCAP] = (unsigned(*)[SCAP])(smem + 0);       // 24 KiB
  unsigned (*sIn)[ICAP]  = (unsigned(*)[ICAP])(smem + 24576);   // 3 KiB
  int*  sSCnt     = (int*)(smem + 27648);
  int*  sICnt     = (int*)(smem + 27840);
  ull*  sRemv     = (ull*)(smem + 28032);      // 1 KiB
  u16*  sKeptList = (u16*)(smem + 29056);      // 4000 B
  float4* sWB     = (float4*)(smem + 33056);
  float*  sWA     = (float*)(smem + 34080);
  ull*  sSupW     = (ull*)(smem + 34336);
  int*  sCtl      = (int*)(smem + 34344);      // [0]=base [1]=stop [2]=over

  // pre-spin: sRemv from area sign (K1 output via kernel boundary — proven)
  {
    int wave = tid >> 6, lane = tid & 63;
    for (int w = wave; w < NWORDS; w += 4) {
      float a = area[w * 64 + lane];
      ull inv = __ballot(a < 0.0f);
      if (lane == 0) sRemv[w] = inv;
    }
  }
  if (tid == 254) sCtl[0] = 0;
  if (tid == 253) sCtl[1] = 0;

  // wait for all pairs blocks (relaxed agent poll, proven r12/r13/r16)
  if (tid == 0) {
    while (__hip_atomic_load(&ctrl[49], __ATOMIC_RELAXED,
                             __HIP_MEMORY_SCOPE_AGENT) < NUNITS)
      __builtin_amdgcn_s_sleep(2);
  }
  __syncthreads();

  // payload staging: 4-wide unrolled agent atomic loads (4 in flight)
  if (tid < MASKW) { sSCnt[tid] = aloadi(&ctrl[tid]); sICnt[tid] = aloadi(&inCnt[tid]); }
  if (tid == 255) sCtl[2] = aloadi(&ctrl[48]);
  for (int k = tid * 4; k < MASKW * SCAP; k += 1024) {
    unsigned a0 = aload(&srcBuf[k + 0]);
    unsigned a1 = aload(&srcBuf[k + 1]);
    unsigned a2 = aload(&srcBuf[k + 2]);
    unsigned a3 = aload(&srcBuf[k + 3]);
    ((unsigned*)sSrc)[k + 0] = a0;
    ((unsigned*)sSrc)[k + 1] = a1;
    ((unsigned*)sSrc)[k + 2] = a2;
    ((unsigned*)sSrc)[k + 3] = a3;
  }
  for (int k = tid; k < MASKW * ICAP; k += 256)
    ((unsigned*)sIn)[k] = aload(&inBuf[k]);
  __syncthreads();

  int sOver = sCtl[2];
  // ---- sparse masked phase (wave 0 only; no shfl/reduce in the loop)
  if (!sOver && tid < 64) {
    int lane = tid;
    int base = 0;
    for (int w = 0; w < MASKW; ++w) {
      ull avail = ~sRemv[w];                   // in-order LDS: sees all ORs
      int cnI = sICnt[w];
      ull kept;
      if (cnI == 0) {
        kept = avail;
      } else {
        ull dgT = 0ull;                        // my in-word suppressors
        for (int k = 0; k < cnI; ++k) {
          unsigned p = sIn[w][k];              // uniform LDS read
          int il = (int)(p & 63u);
          int jl = (int)(p >> 8) & 63;
          if (lane == jl) dgT |= 1ull << il;
        }
        ull cf = __ballot(((dgT & avail) != 0ull) && ((avail >> lane) & 1ull));
        if (cf == 0ull) {
          kept = avail;
        } else {
          kept = avail;
          while (true) {                       // fixpoint == greedy
            bool sup = (dgT & kept) != 0ull;
            ull kn = avail & ~__ballot(sup);
            if (kn == kept) break;
            kept = kn;
          }
        }
      }
      if ((kept >> lane) & 1ull) {
        int rank = base + (int)__popcll(kept & ((1ull << lane) - 1ull));
        if (rank < NPOST) sKeptList[rank] = (u16)(w * 64 + lane);
      }
      base += (int)__popcll(kept);
      if (base >= NPOST) break;                // ranks >=2000 never emitted
      // eager push-forward: lane-parallel, no reduction
      int cnS = sSCnt[w];
      for (int k = lane; k < cnS; k += 64) {
        unsigned p = sSrc[w][k];
        int il = (int)(p >> 13) & 63;
        if ((kept >> il) & 1ull) {
          int wt = (int)(p >> 6) & 127;
          atomicOr(&sRemv[wt], 1ull << (p & 63u));   // LDS atomic
        }
      }
    }
    if (lane == 0) { sCtl[0] = base; if (base >= NPOST) sCtl[1] = 1; }
  }
  __syncthreads();

  // ---- dense fallback (correctness only; not hit by the bench input)
  int startW = sOver ? 0 : MASKW;
  if (!sCtl[1]) {
    for (int w = startW; w < NWORDS; ++w) {
      if (tid < 64) { sWB[tid] = bs[w * 64 + tid]; sWA[tid] = area[w * 64 + tid]; }
      if (tid == 0) *sSupW = sRemv[w];
      __syncthreads();
      int nk = sCtl[0];
      int c = tid & 63;
      for (int k0 = tid >> 6; k0 < nk; k0 += 4) {   // wave per kept box
        int ki = sKeptList[k0];
        float4 kb = bs[ki];                         // uniform load
        bool s = iou_gt_thr(kb, area[ki], sWB[c], sWA[c]);
        ull bits = __ballot(s);
        if (c == 0 && bits) atomicOr(sSupW, bits);
      }
      __syncthreads();
      if (tid < 64) {
        int lane = tid;
        float4 bm = sWB[lane];
        float am = sWA[lane];
        ull dg = 0;
        if (am >= 0.0f) {
          for (int cc = lane + 1; cc < 64; ++cc)
            if (sWA[cc] >= 0.0f && iou_gt_thr(bm, am, sWB[cc], sWA[cc]))
              dg |= 1ull << cc;
        }
        ull avail = ~*sSupW;
        ull kept = resolve_word(dg, avail, lane);
        int base = sCtl[0];
        if ((kept >> lane) & 1ull) {
          int rank = base + (int)__popcll(kept & ((1ull << lane) - 1ull));
          if (rank < NPOST) sKeptList[rank] = (u16)(w * 64 + lane);
        }
        if (lane == 0) {
          int nb = base + (int)__popcll(kept);
          sCtl[0] = nb;
          if (nb >= NPOST) sCtl[1] = 1;
        }
      }
      __syncthreads();
      if (sCtl[1]) break;
    }
  }

  __syncthreads();
  int total = sCtl[0];
  if (total > NPOST) total = NPOST;
  for (int r = tid; r < NPOST; r += 256) {
    float4 v = make_float4(0.0f, 0.0f, 0.0f, 0.0f);
    if (r < total) v = bs[sKeptList[r]];
    reinterpret_cast<float4*>(out)[r] = v;
  }
  // beacon: self-diagnose a repeat failure (never fires on a healthy run)
  if (total == 0 && tid == 0)
    out[0] = 5.0e9f + (float)sCtl[2] * 1.0e8f;
}

// ---------------------------------------------------------------------------
extern "C" void kernel_launch(void* const* d_in, const int* in_sizes, int n_in,
                              void* d_out, int out_size, void* d_ws, size_t ws_size,
                              hipStream_t stream) {
  const float* locs   = (const float*)d_in[0];   // (8192,4) cy,cx,h,w
  const float* scores = (const float*)d_in[1];   // (8192,)

  char* ws = (char*)d_ws;
  float4*   bs       = (float4*)(ws + 0);
  float*    area     = (float*)(ws + 131072);
  int*      ctrl     = (int*)(ws + 163840);
  int*      inCnt    = (int*)(ws + 164096);
  unsigned* srcBuf   = (unsigned*)(ws + 164352);
  unsigned* inBuf    = (unsigned*)(ws + 188928);

  rankgather_kernel<<<N / 8, 256, 0, stream>>>(locs, scores, bs, area, ctrl, inCnt);
  pairscan_kernel<<<NUNITS + 1, 256, 0, stream>>>(
      bs, area, ctrl, inCnt, srcBuf, inBuf, (float*)d_out);
}

// Round 20
// 60.036 us; speedup vs baseline: 2.7064x; 1.0541x over previous
//
#include <hip/hip_runtime.h>
#include <cstdint>
#include <cstddef>

typedef unsigned long long ull;
typedef unsigned short u16;

#define N 8192
#define NWORDS 128          // 8192 / 64
#define NPOST 2000
#define NMS_THR 0.7f
#define MASKW 48            // words covered by sparse conflict pairs (stop ~34)
#define SCAP 128            // cross-word pair cap per SOURCE word
#define ICAP 16             // in-word pair cap per word
#define NUNITS 312          // pair units: sum_{cbq<12} 4(cbq+1) = 312
#define SLICE_STRIDE 260    // floats; 1040B: parts hit disjoint banks

// ---------------- ws layout ----------------
// 0      : bs       float4[8192]  128 KiB (sorted clipped boxes)
// 131072 : area     f32[8192]     32 KiB  (-1.0 marks invalid box)
// 163840 : ctrl     i32[64]       ([0..47] srcCnt, [48] overflow, [49] done)
// 164096 : inCnt    i32[64]
// 164352 : srcBuf   u32[48*128]   24 KiB  ((il<<13)|(wt<<6)|jl, bucket=src word)
// 188928 : inBuf    u32[48*16]    3 KiB   ((jl<<8)|il per in-word pair)

// ---------------------------------------------------------------------------
__device__ __forceinline__ float4 decode_clip_box(const float4 L, bool* valid) {
#pragma clang fp contract(off)
  float cy = L.x, cx = L.y, h = L.z, w = L.w;
  float y1 = cy - 0.5f * h;
  float x1 = cx - 0.5f * w;
  float y2 = cy + 0.5f * h;
  float x2 = cx + 0.5f * w;
  *valid = ((y2 - y1) > 16.0f) && ((x2 - x1) > 16.0f);
  float4 b;
  b.x = fminf(fmaxf(y1, 0.0f), 800.0f);
  b.y = fminf(fmaxf(x1, 0.0f), 800.0f);
  b.z = fminf(fmaxf(y2, 0.0f), 800.0f);
  b.w = fminf(fmaxf(x2, 0.0f), 800.0f);
  return b;
}

__device__ __forceinline__ float box_area(const float4 b) {
#pragma clang fp contract(off)
  return (b.z - b.x) * (b.w - b.y);   // clipped => always >= 0
}

__device__ __forceinline__ bool iou_gt_thr(const float4 a, float aa,
                                           const float4 b, float ab) {
#pragma clang fp contract(off)
  float iy = fminf(a.z, b.z) - fmaxf(a.x, b.x);
  float ix = fminf(a.w, b.w) - fmaxf(a.y, b.y);
  iy = fmaxf(iy, 0.0f);
  ix = fmaxf(ix, 0.0f);
  float inter = iy * ix;
  float uni = aa + ab - inter;
  // exact IEEE division: predicate must bit-match the numpy reference
  return (inter > 0.0f) && (uni > 0.0f) && ((inter / uni) > NMS_THR);
}

// Greedy within-word resolve from dense "who-I-suppress" (fallback only).
__device__ __forceinline__ ull resolve_word(ull dg, ull avail, int lane) {
  ull conflict = __ballot(((dg & avail) != 0ull) && ((avail >> lane) & 1ull));
  if (conflict == 0ull) return avail;
  ull dgT = 0ull;
  #pragma unroll
  for (int c = 0; c < 64; ++c) {
    ull tb = __ballot((dg >> c) & 1ull);
    if (lane == c) dgT = tb;
  }
  ull kept = avail;
  while (true) {                 // fixpoint == greedy (prefix-stabilization)
    bool sup = (dgT & kept) != 0ull;
    ull kn = avail & ~__ballot(sup);
    if (kn == kept) break;
    kept = kn;
  }
  return kept;
}

__device__ __forceinline__ unsigned aload(const unsigned* p) {
  return __hip_atomic_load(p, __ATOMIC_RELAXED, __HIP_MEMORY_SCOPE_AGENT);
}
__device__ __forceinline__ int aloadi(const int* p) {
  return __hip_atomic_load(p, __ATOMIC_RELAXED, __HIP_MEMORY_SCOPE_AGENT);
}

// ===========================================================================
// K1: rank + gather, fused.  GRID = N/8 = 1024 blocks (proven r19: ~<12us).
// ===========================================================================
__global__ __launch_bounds__(256) void rankgather_kernel(
    const float* __restrict__ locs, const float* __restrict__ scores,
    float4* __restrict__ bs, float* __restrict__ area,
    int* __restrict__ ctrl, int* __restrict__ inCnt) {
  __shared__ float ssc[32 * SLICE_STRIDE];   // 33280 B, slices of 256 + pad
  __shared__ int sRank[8][33];               // +1 pad: conflict-free
  int tid = threadIdx.x, bid = blockIdx.x;
  if (bid == 0) {
    if (tid < 64) ctrl[tid] = 0;
    else if (tid < 128) inCnt[tid - 64] = 0;
  }
  const float4* locs4 = (const float4*)locs;
  for (int k = 0; k < 32; ++k) {
    int j = k * 256 + tid;                   // coalesced
    bool v; (void)decode_clip_box(locs4[j], &v);
    float s = v ? scores[j] : -__builtin_inff();
    ssc[(j >> 8) * SLICE_STRIDE + (j & 255)] = s;
  }
  __syncthreads();
  int boxOff = tid & 7;
  int part = tid >> 3;                       // 32 slices of 256 scores
  int i = bid * 8 + boxOff;
  float si = ssc[(i >> 8) * SLICE_STRIDE + (i & 255)];
  const float4* s4 = (const float4*)(ssc + part * SLICE_STRIDE);
  int j0 = part * 256;
  int cnt = 0;
  // j precedes i <=> s_j > s_i || (s_j == s_i && j < i)  (stable descending)
  for (int q = 0; q < 64; ++q) {
    float4 v = s4[q];                        // 8 distinct banksets: no conflict
    int j = j0 + 4 * q;
    cnt += (v.x > si) || ((v.x == si) & ((j + 0) < i));
    cnt += (v.y > si) || ((v.y == si) & ((j + 1) < i));
    cnt += (v.z > si) || ((v.z == si) & ((j + 2) < i));
    cnt += (v.w > si) || ((v.w == si) & ((j + 3) < i));
  }
  sRank[boxOff][part] = cnt;
  __syncthreads();
  if (tid < 8) {
    int r = 0;
    #pragma unroll
    for (int p = 0; p < 32; ++p) r += sRank[tid][p];
    int ig = bid * 8 + tid;
    bool v;
    float4 b = decode_clip_box(locs4[ig], &v);
    bs[r] = b;
    area[r] = v ? box_area(b) : -1.0f;       // sign encodes validity
  }
}

// ===========================================================================
// K2: pairs (blocks 1..312) + scan (block 0), single dispatch.
// r20 changes (block 0 only): payload staging via PLAIN uint4 loads (launch
// acquire invalidates L2; no block on this XCD reads srcBuf before the spin
// exits; producers' agent stores bypass local L2 -> plain loads read fresh
// LLC data), and pre-spin sRemv built with 8-deep batched loads.
// ===========================================================================
__global__ __launch_bounds__(256) void pairscan_kernel(
    const float4* __restrict__ bs, const float* __restrict__ area,
    int* __restrict__ ctrl, int* __restrict__ inCnt,
    unsigned* __restrict__ srcBuf, unsigned* __restrict__ inBuf,
    float* __restrict__ out) {
  __shared__ __align__(16) char smem[35840];
  int tid = threadIdx.x, bid = blockIdx.x;

  if (bid > 0) {
    // ---------------- pairs unit u = bid-1 (byte-identical to r19) --------
    float4* sb = (float4*)smem;               // [4][64]
    float*  sa = (float*)(smem + 4096);       // [4][64]
    int u = bid - 1;
    int cbq = 0;                              // largest c with 2c(c+1) <= u
    while (2 * (cbq + 1) * (cbq + 2) <= u) ++cbq;
    int rb = u - 2 * cbq * (cbq + 1);
    int lane = tid & 63, cq = tid >> 6;
    int cb = cbq * 4 + cq;
    int j0 = cb * 64;
    sb[cq * 64 + lane] = bs[j0 + lane];
    sa[cq * 64 + lane] = area[j0 + lane];
    int i = rb * 64 + lane;
    float4 r = bs[i];
    float ai = area[i];
    __syncthreads();
    if (cb >= rb && ai >= 0.0f) {             // invalid i never pairs
      ull bits = 0;
      for (int c = 0; c < 64; ++c) {
        if ((j0 + c) > i && sa[cq * 64 + c] >= 0.0f &&
            iou_gt_thr(r, ai, sb[cq * 64 + c], sa[cq * 64 + c]))
          bits |= 1ull << c;
      }
      int n = (int)__popcll(bits);
      if (n) {
        if (cb == rb) {                       // in-word pairs (bucket = word)
          int base = atomicAdd(&inCnt[cb], n);
          if (base + n > ICAP) {
            __hip_atomic_store(&ctrl[48], 1, __ATOMIC_RELAXED,
                               __HIP_MEMORY_SCOPE_AGENT);
          } else {
            int k = base;
            while (bits) {
              int c = (int)__builtin_ctzll(bits); bits &= bits - 1;
              __hip_atomic_store(&inBuf[cb * ICAP + k++],
                                 ((unsigned)c << 8) | (unsigned)lane,
                                 __ATOMIC_RELAXED, __HIP_MEMORY_SCOPE_AGENT);
            }
          }
        } else {                              // cross pairs, bucket = SOURCE rb
          int base = atomicAdd(&ctrl[rb], n);
          if (base + n > SCAP) {
            __hip_atomic_store(&ctrl[48], 1, __ATOMIC_RELAXED,
                               __HIP_MEMORY_SCOPE_AGENT);
          } else {
            int k = base;
            while (bits) {
              int c = (int)__builtin_ctzll(bits); bits &= bits - 1;
              // (il<<13) | (wt<<6) | jl
              __hip_atomic_store(&srcBuf[rb * SCAP + k++],
                                 ((unsigned)lane << 13) | ((unsigned)cb << 6) |
                                     (unsigned)c,
                                 __ATOMIC_RELAXED, __HIP_MEMORY_SCOPE_AGENT);
            }
          }
        }
      }
    }
    __syncthreads();   // drains vmcnt(0): payload stores acked at LLC here
    if (tid == 0)
      __hip_atomic_fetch_add(&ctrl[49], 1, __ATOMIC_RELAXED,
                             __HIP_MEMORY_SCOPE_AGENT);
    return;
  }

  // ---------------- scan (block 0) ----------------
  unsigned (*sSrc)[SCAP] = (unsigned(*)[SCAP])(smem + 0);       // 24 KiB
  unsigned (*sIn)[ICAP]  = (unsigned(*)[ICAP])(smem + 24576);   // 3 KiB
  int*  sSCnt     = (int*)(smem + 27648);
  int*  sICnt     = (int*)(smem + 27840);
  ull*  sRemv     = (ull*)(smem + 28032);      // 1 KiB
  u16*  sKeptList = (u16*)(smem + 29056);      // 4000 B
  float4* sWB     = (float4*)(smem + 33056);
  float*  sWA     = (float*)(smem + 34080);
  ull*  sSupW     = (ull*)(smem + 34336);
  int*  sCtl      = (int*)(smem + 34344);      // [0]=base [1]=stop [2]=over

  // pre-spin: sRemv from area sign, 8-deep batched loads (K1 output fresh
  // via kernel-launch acquire — proven by replay validation since r12)
  {
    int wave = tid >> 6, lane = tid & 63;
    for (int b = 0; b < 4; ++b) {
      float av[8];
      #pragma unroll
      for (int q = 0; q < 8; ++q)
        av[q] = area[(wave + (b * 8 + q) * 4) * 64 + lane];
      #pragma unroll
      for (int q = 0; q < 8; ++q) {
        ull inv = __ballot(av[q] < 0.0f);
        if (lane == 0) sRemv[wave + (b * 8 + q) * 4] = inv;
      }
    }
  }
  if (tid == 254) sCtl[0] = 0;
  if (tid == 253) sCtl[1] = 0;

  // wait for all pairs blocks (relaxed agent poll, proven r12..r19)
  if (tid == 0) {
    while (__hip_atomic_load(&ctrl[49], __ATOMIC_RELAXED,
                             __HIP_MEMORY_SCOPE_AGENT) < NUNITS)
      __builtin_amdgcn_s_sleep(2);
  }
  __syncthreads();

  // counts via agent loads (few); payload via PLAIN vectorized loads
  if (tid < MASKW) { sSCnt[tid] = aloadi(&ctrl[tid]); sICnt[tid] = aloadi(&inCnt[tid]); }
  if (tid == 255) sCtl[2] = aloadi(&ctrl[48]);
  {
    const uint4* src4 = (const uint4*)srcBuf;          // 1536 uint4
    uint4* dst4 = (uint4*)sSrc;
    #pragma unroll
    for (int k = 0; k < 6; ++k) dst4[tid + k * 256] = src4[tid + k * 256];
    const uint4* in4 = (const uint4*)inBuf;            // 192 uint4
    if (tid < 192) ((uint4*)sIn)[tid] = in4[tid];
  }
  __syncthreads();

  int sOver = sCtl[2];
  // ---- sparse masked phase (wave 0 only; no shfl/reduce in the loop)
  if (!sOver && tid < 64) {
    int lane = tid;
    int base = 0;
    for (int w = 0; w < MASKW; ++w) {
      ull avail = ~sRemv[w];                   // in-order LDS: sees all ORs
      int cnI = sICnt[w];
      ull kept;
      if (cnI == 0) {
        kept = avail;
      } else {
        ull dgT = 0ull;                        // my in-word suppressors
        for (int k = 0; k < cnI; ++k) {
          unsigned p = sIn[w][k];              // uniform LDS read
          int il = (int)(p & 63u);
          int jl = (int)(p >> 8) & 63;
          if (lane == jl) dgT |= 1ull << il;
        }
        ull cf = __ballot(((dgT & avail) != 0ull) && ((avail >> lane) & 1ull));
        if (cf == 0ull) {
          kept = avail;
        } else {
          kept = avail;
          while (true) {                       // fixpoint == greedy
            bool sup = (dgT & kept) != 0ull;
            ull kn = avail & ~__ballot(sup);
            if (kn == kept) break;
            kept = kn;
          }
        }
      }
      if ((kept >> lane) & 1ull) {
        int rank = base + (int)__popcll(kept & ((1ull << lane) - 1ull));
        if (rank < NPOST) sKeptList[rank] = (u16)(w * 64 + lane);
      }
      base += (int)__popcll(kept);
      if (base >= NPOST) break;                // ranks >=2000 never emitted
      // eager push-forward: lane-parallel, no reduction
      int cnS = sSCnt[w];
      for (int k = lane; k < cnS; k += 64) {
        unsigned p = sSrc[w][k];
        int il = (int)(p >> 13) & 63;
        if ((kept >> il) & 1ull) {
          int wt = (int)(p >> 6) & 127;
          atomicOr(&sRemv[wt], 1ull << (p & 63u));   // LDS atomic
        }
      }
    }
    if (lane == 0) { sCtl[0] = base; if (base >= NPOST) sCtl[1] = 1; }
  }
  __syncthreads();

  // ---- dense fallback (correctness only; not hit by the bench input)
  int startW = sOver ? 0 : MASKW;
  if (!sCtl[1]) {
    for (int w = startW; w < NWORDS; ++w) {
      if (tid < 64) { sWB[tid] = bs[w * 64 + tid]; sWA[tid] = area[w * 64 + tid]; }
      if (tid == 0) *sSupW = sRemv[w];
      __syncthreads();
      int nk = sCtl[0];
      int c = tid & 63;
      for (int k0 = tid >> 6; k0 < nk; k0 += 4) {   // wave per kept box
        int ki = sKeptList[k0];
        float4 kb = bs[ki];                         // uniform load
        bool s = iou_gt_thr(kb, area[ki], sWB[c], sWA[c]);
        ull bits = __ballot(s);
        if (c == 0 && bits) atomicOr(sSupW, bits);
      }
      __syncthreads();
      if (tid < 64) {
        int lane = tid;
        float4 bm = sWB[lane];
        float am = sWA[lane];
        ull dg = 0;
        if (am >= 0.0f) {
          for (int cc = lane + 1; cc < 64; ++cc)
            if (sWA[cc] >= 0.0f && iou_gt_thr(bm, am, sWB[cc], sWA[cc]))
              dg |= 1ull << cc;
        }
        ull avail = ~*sSupW;
        ull kept = resolve_word(dg, avail, lane);
        int base = sCtl[0];
        if ((kept >> lane) & 1ull) {
          int rank = base + (int)__popcll(kept & ((1ull << lane) - 1ull));
          if (rank < NPOST) sKeptList[rank] = (u16)(w * 64 + lane);
        }
        if (lane == 0) {
          int nb = base + (int)__popcll(kept);
          sCtl[0] = nb;
          if (nb >= NPOST) sCtl[1] = 1;
        }
      }
      __syncthreads();
      if (sCtl[1]) break;
    }
  }

  __syncthreads();
  int total = sCtl[0];
  if (total > NPOST) total = NPOST;
  for (int r = tid; r < NPOST; r += 256) {
    float4 v = make_float4(0.0f, 0.0f, 0.0f, 0.0f);
    if (r < total) v = bs[sKeptList[r]];
    reinterpret_cast<float4*>(out)[r] = v;
  }
  // beacon: self-diagnose a repeat failure (never fires on a healthy run)
  if (total == 0 && tid == 0)
    out[0] = 5.0e9f + (float)sCtl[2] * 1.0e8f;
}

// ---------------------------------------------------------------------------
extern "C" void kernel_launch(void* const* d_in, const int* in_sizes, int n_in,
                              void* d_out, int out_size, void* d_ws, size_t ws_size,
                              hipStream_t stream) {
  const float* locs   = (const float*)d_in[0];   // (8192,4) cy,cx,h,w
  const float* scores = (const float*)d_in[1];   // (8192,)

  char* ws = (char*)d_ws;
  float4*   bs       = (float4*)(ws + 0);
  float*    area     = (float*)(ws + 131072);
  int*      ctrl     = (int*)(ws + 163840);
  int*      inCnt    = (int*)(ws + 164096);
  unsigned* srcBuf   = (unsigned*)(ws + 164352);
  unsigned* inBuf    = (unsigned*)(ws + 188928);

  rankgather_kernel<<<N / 8, 256, 0, stream>>>(locs, scores, bs, area, ctrl, inCnt);
  pairscan_kernel<<<NUNITS + 1, 256, 0, stream>>>(
      bs, area, ctrl, inCnt, srcBuf, inBuf, (float*)d_out);
}